// Round 16
// baseline (983.788 us; speedup 1.0000x reference)
//
#include <hip/hip_runtime.h>

#define OFFX 0.0f
#define OFFY -40.0f
#define OFFZ -3.0f
#define BNEPS 1e-3f
#define NCH 128   // bn partial chunks
#define NG 9      // conv tap groups (3 taps each)

typedef _Float16 h2_t __attribute__((ext_vector_type(2)));
__device__ inline h2_t u2h(unsigned u) { union { unsigned u; h2_t h; } x; x.u = u; return x.h; }
__device__ inline unsigned h2u(h2_t h) { union { unsigned u; h2_t h; } x; x.h = h; return x.u; }

// ---------------- keys ----------------
__global__ void keys_k(const int* __restrict__ coords, int n, int D, int H, int W,
                       int* __restrict__ keys) {
  int i = blockIdx.x * 256 + threadIdx.x;
  if (i < n) {
    const int* c = coords + (size_t)i * 4;
    keys[i] = ((c[0] * D + c[1]) * H + c[2]) * W + c[3];
  }
}

// ---------------- neighbor tables ----------------
__global__ void nbr_k(const int* __restrict__ coords, int np, const int* __restrict__ keys, int nk,
                      int D, int H, int W, int scale, int* __restrict__ nbr) {
  int t = blockIdx.x * 256 + threadIdx.x;
  if (t >= np * 27) return;
  int p = t / 27, k = t % 27;
  int kz = k / 9 - 1, ky = (k / 3) % 3 - 1, kx = k % 3 - 1;
  const int* c = coords + (size_t)p * 4;
  int z = c[1] * scale + kz, y = c[2] * scale + ky, x = c[3] * scale + kx;
  int r = -1;
  if (z >= 0 && z < D && y >= 0 && y < H && x >= 0 && x < W) {
    int q = ((c[0] * D + z) * H + y) * W + x;
    int lo = 0, hi = nk;
    while (lo < hi) { int m = (lo + hi) >> 1; if (keys[m] < q) lo = m + 1; else hi = m; }
    if (lo < nk && keys[lo] == q) r = lo;
  }
  nbr[t] = r;
}

// ---------------- weight prep: fp32 [27][CIN][COUT] -> h2 [27][CIN/2][COUT] ----------------
struct WPrep { const float* src; unsigned* dst; int cin; int cout; };
struct WP13 { WPrep l[13]; };
__global__ void wprep_k(WP13 a) {
  WPrep w = a.l[blockIdx.y];
  int cp2 = w.cin / 2;
  int tot = 27 * cp2 * w.cout;
  int i = blockIdx.x * 256 + threadIdx.x;
  if (i >= tot) return;
  int o = i % w.cout, rest = i / w.cout;
  int cp = rest % cp2, k = rest / cp2;
  float lo = w.src[((size_t)k * w.cin + 2 * cp) * w.cout + o];
  float hi = w.src[((size_t)k * w.cin + 2 * cp + 1) * w.cout + o];
  h2_t h; h[0] = (_Float16)lo; h[1] = (_Float16)hi;
  w.dst[i] = h2u(h);
}

// ---------------- layer-0 conv (fp32, CIN=4): LDS tile-GEMM TP=32 ----------------
template<int CIN, int COUT>
__global__ __launch_bounds__(128) void convg_k(const float* __restrict__ feats,
                                               const int* __restrict__ nbr,
                                               const float* __restrict__ w, int n,
                                               float* __restrict__ partial, int gstride) {
  constexpr int TP = 32;
  constexpr int LDP = 36;
  constexpr int CO = COUT / 16;
  __shared__ float G[CIN * LDP];
  int tid = threadIdx.x;
  int pg = tid >> 4, cg = tid & 15;
  int p0 = blockIdx.x * TP;
  int k0 = blockIdx.y * 3;
  float acc[4][CO];
#pragma unroll
  for (int i = 0; i < 4; i++)
#pragma unroll
    for (int j = 0; j < CO; j++) acc[i][j] = 0.f;

  for (int kk = 0; kk < 3; kk++) {
    int k = k0 + kk;
    __syncthreads();
    for (int ch = tid; ch < TP * CIN / 4; ch += 128) {
      int r = ch & (TP - 1), c4 = ch / TP;
      int p = p0 + r;
      int idx = (p < n) ? nbr[(size_t)p * 27 + k] : -1;
      float4 fv = make_float4(0.f, 0.f, 0.f, 0.f);
      if (idx >= 0) fv = *(const float4*)(feats + (size_t)idx * CIN + c4 * 4);
      G[(c4 * 4 + 0) * LDP + r] = fv.x;
      G[(c4 * 4 + 1) * LDP + r] = fv.y;
      G[(c4 * 4 + 2) * LDP + r] = fv.z;
      G[(c4 * 4 + 3) * LDP + r] = fv.w;
    }
    __syncthreads();
    const float* wk = w + (size_t)k * CIN * COUT + cg * CO;
#pragma unroll
    for (int c = 0; c < CIN; c++) {
      float4 g4 = *(const float4*)&G[c * LDP + pg * 4];
      float wv[CO];
      if constexpr (CO == 4)      *(float4*)wv = *(const float4*)(wk + c * COUT);
      else if constexpr (CO == 2) *(float2*)wv = *(const float2*)(wk + c * COUT);
      else                        wv[0] = wk[c * COUT];
      float gp[4] = {g4.x, g4.y, g4.z, g4.w};
#pragma unroll
      for (int i = 0; i < 4; i++)
#pragma unroll
        for (int j = 0; j < CO; j++) acc[i][j] = fmaf(gp[i], wv[j], acc[i][j]);
    }
  }
#pragma unroll
  for (int i = 0; i < 4; i++) {
    int p = p0 + pg * 4 + i;
    if (p < n) {
      float* dst = partial + (size_t)blockIdx.y * gstride + (size_t)p * COUT + cg * CO;
      if constexpr (CO == 4)      *(float4*)dst = *(float4*)acc[i];
      else if constexpr (CO == 2) *(float2*)dst = *(float2*)acc[i];
      else                        dst[0] = acc[i][0];
    }
  }
}

// ---------------- f16 conv: software-pipelined gather, fdot2, fused BN+ReLU ----------------
template<int CIN, int COUT>
__global__ __launch_bounds__(128) void convh_k(const unsigned* __restrict__ fh,
                                               const int* __restrict__ nbr,
                                               const unsigned* __restrict__ wh, int n,
                                               float* __restrict__ partial, int gstride,
                                               const float* __restrict__ scsh) {
  constexpr int TP = 32;
  constexpr int LDPH = 36;
  constexpr int CO = COUT / 16;
  constexpr int CP = CIN / 2;
  __shared__ unsigned H[CP * LDPH];
  int tid = threadIdx.x;
  int pg = tid >> 4, cg = tid & 15;
  int p0 = blockIdx.x * TP;
  int k0 = blockIdx.y * 3;
  int r = tid & 31;
  int p = p0 + r;
  int sidx[3];
  if (p < n) {
    const int* nb = nbr + (size_t)p * 27 + k0;
    sidx[0] = nb[0]; sidx[1] = nb[1]; sidx[2] = nb[2];
  } else { sidx[0] = sidx[1] = sidx[2] = -1; }

  float acc[4][CO];
#pragma unroll
  for (int i = 0; i < 4; i++)
#pragma unroll
    for (int j = 0; j < CO; j++) acc[i][j] = 0.f;

  if constexpr (CIN >= 32) {
    constexpr int NLD = CIN / 32;
    uint4 pf[NLD];
    {
      int idx = sidx[0];
#pragma unroll
      for (int it = 0; it < NLD; it++) {
        int q = (tid >> 5) + it * 4;
        pf[it] = (idx >= 0) ? *(const uint4*)(fh + (size_t)idx * CP + q * 4)
                            : make_uint4(0, 0, 0, 0);
      }
    }
    for (int kk = 0; kk < 3; kk++) {
      bool ok = sidx[kk] >= 0;
      __syncthreads();
#pragma unroll
      for (int it = 0; it < NLD; it++) {
        int q = (tid >> 5) + it * 4;
        unsigned uu[4] = {pf[it].x, pf[it].y, pf[it].z, pf[it].w};
#pragma unroll
        for (int j = 0; j < 4; j++) {
          int cp = q * 4 + j;
          unsigned outw = 0;
          if (ok) {
            h2_t h = u2h(uu[j]);
            float lo = fmaxf(fmaf((float)h[0], scsh[2 * cp], scsh[CIN + 2 * cp]), 0.f);
            float hi = fmaxf(fmaf((float)h[1], scsh[2 * cp + 1], scsh[CIN + 2 * cp + 1]), 0.f);
            h2_t o; o[0] = (_Float16)lo; o[1] = (_Float16)hi;
            outw = h2u(o);
          }
          H[cp * LDPH + r] = outw;
        }
      }
      if (kk < 2) {
        int idx = sidx[kk + 1];
#pragma unroll
        for (int it = 0; it < NLD; it++) {
          int q = (tid >> 5) + it * 4;
          pf[it] = (idx >= 0) ? *(const uint4*)(fh + (size_t)idx * CP + q * 4)
                              : make_uint4(0, 0, 0, 0);
        }
      }
      __syncthreads();
      const unsigned* wk = wh + (size_t)(k0 + kk) * CP * COUT + cg * CO;
#pragma unroll 8
      for (int cp = 0; cp < CP; cp++) {
        uint4 g4 = *(const uint4*)&H[cp * LDPH + pg * 4];
        unsigned gg[4] = {g4.x, g4.y, g4.z, g4.w};
        unsigned wv[CO];
        if constexpr (CO == 4)      *(uint4*)wv = *(const uint4*)(wk + cp * COUT);
        else if constexpr (CO == 2) *(uint2*)wv = *(const uint2*)(wk + cp * COUT);
        else                        wv[0] = wk[cp * COUT];
#pragma unroll
        for (int i = 0; i < 4; i++)
#pragma unroll
          for (int j = 0; j < CO; j++)
            acc[i][j] = __builtin_amdgcn_fdot2(u2h(gg[i]), u2h(wv[j]), acc[i][j], false);
      }
    }
  } else {  // CIN == 16
    int q = tid >> 5;
    uint2 pf2;
    {
      int idx = sidx[0];
      pf2 = (idx >= 0) ? *(const uint2*)(fh + (size_t)idx * CP + q * 2) : make_uint2(0, 0);
    }
    for (int kk = 0; kk < 3; kk++) {
      bool ok = sidx[kk] >= 0;
      __syncthreads();
      unsigned uu[2] = {pf2.x, pf2.y};
#pragma unroll
      for (int j = 0; j < 2; j++) {
        int cp = q * 2 + j;
        unsigned outw = 0;
        if (ok) {
          h2_t h = u2h(uu[j]);
          float lo = fmaxf(fmaf((float)h[0], scsh[2 * cp], scsh[CIN + 2 * cp]), 0.f);
          float hi = fmaxf(fmaf((float)h[1], scsh[2 * cp + 1], scsh[CIN + 2 * cp + 1]), 0.f);
          h2_t o; o[0] = (_Float16)lo; o[1] = (_Float16)hi;
          outw = h2u(o);
        }
        H[cp * LDPH + r] = outw;
      }
      if (kk < 2) {
        int idx = sidx[kk + 1];
        pf2 = (idx >= 0) ? *(const uint2*)(fh + (size_t)idx * CP + q * 2) : make_uint2(0, 0);
      }
      __syncthreads();
      const unsigned* wk = wh + (size_t)(k0 + kk) * CP * COUT + cg * CO;
#pragma unroll
      for (int cp = 0; cp < CP; cp++) {
        uint4 g4 = *(const uint4*)&H[cp * LDPH + pg * 4];
        unsigned gg[4] = {g4.x, g4.y, g4.z, g4.w};
        unsigned wv[CO];
        if constexpr (CO == 4)      *(uint4*)wv = *(const uint4*)(wk + cp * COUT);
        else if constexpr (CO == 2) *(uint2*)wv = *(const uint2*)(wk + cp * COUT);
        else                        wv[0] = wk[cp * COUT];
#pragma unroll
        for (int i = 0; i < 4; i++)
#pragma unroll
          for (int j = 0; j < CO; j++)
            acc[i][j] = __builtin_amdgcn_fdot2(u2h(gg[i]), u2h(wv[j]), acc[i][j], false);
      }
    }
  }
#pragma unroll
  for (int i = 0; i < 4; i++) {
    int pp = p0 + pg * 4 + i;
    if (pp < n) {
      float* dst = partial + (size_t)blockIdx.y * gstride + (size_t)pp * COUT + cg * CO;
      if constexpr (CO == 4)      *(float4*)dst = *(float4*)acc[i];
      else if constexpr (CO == 2) *(float2*)dst = *(float2*)acc[i];
      else                        dst[0] = acc[i][0];
    }
  }
}

// ---------------- bn: sum partials -> pre(opt fp32) + preh (h2) + stats; last block -> (sc, sh) ----------------
__global__ void bn_k(const float* __restrict__ partial, int G, int gstride, int n, int C,
                     float* __restrict__ pre, unsigned* __restrict__ preh,
                     float* __restrict__ stats, const float* __restrict__ bnp,
                     float* __restrict__ scsh, int* __restrict__ ctr) {
  __shared__ float l1e[256], l2e[256], l1o[256], l2o[256];
  __shared__ int lastf;
  int t = threadIdx.x;
  int total = n * C;
  float s1e = 0.f, s2e = 0.f, s1o = 0.f, s2o = 0.f;
  for (int i2 = (blockIdx.x * 256 + t) * 2; i2 < total; i2 += NCH * 512) {
    float v0 = 0.f, v1 = 0.f;
    for (int g = 0; g < G; g++) {
      float2 pv = *(const float2*)(partial + (size_t)g * gstride + i2);
      v0 += pv.x; v1 += pv.y;
    }
    if (pre) *(float2*)(pre + i2) = make_float2(v0, v1);
    h2_t h; h[0] = (_Float16)v0; h[1] = (_Float16)v1;
    preh[i2 >> 1] = h2u(h);
    s1e += v0; s2e += v0 * v0; s1o += v1; s2o += v1 * v1;
  }
  l1e[t] = s1e; l2e[t] = s2e; l1o[t] = s1o; l2o[t] = s2o;
  for (int s = 128; s >= C / 2; s >>= 1) {
    __syncthreads();
    if (t < s) {
      l1e[t] += l1e[t + s]; l2e[t] += l2e[t + s];
      l1o[t] += l1o[t + s]; l2o[t] += l2o[t + s];
    }
  }
  __syncthreads();
  if (t < C / 2) {
    stats[((size_t)blockIdx.x * C + 2 * t) * 2]     = l1e[t];
    stats[((size_t)blockIdx.x * C + 2 * t) * 2 + 1] = l2e[t];
    stats[((size_t)blockIdx.x * C + 2 * t + 1) * 2]     = l1o[t];
    stats[((size_t)blockIdx.x * C + 2 * t + 1) * 2 + 1] = l2o[t];
  }
  __threadfence();
  __syncthreads();
  if (t == 0) lastf = (atomicAdd(ctr, 1) == NCH - 1) ? 1 : 0;
  __syncthreads();
  if (lastf) {
    __threadfence();
    if (t < C) {
      float a1 = 0.f, a2 = 0.f;
      for (int ch = 0; ch < NCH; ch++) {
        a1 += stats[((size_t)ch * C + t) * 2];
        a2 += stats[((size_t)ch * C + t) * 2 + 1];
      }
      float m = a1 / n;
      float v = a2 / n - m * m;
      float sc = bnp[t] / sqrtf(v + BNEPS);
      scsh[t] = sc;
      scsh[C + t] = bnp[C + t] - m * sc;
    }
  }
}

// ---------------- points_mean ----------------
__global__ void pm_k(const float* __restrict__ vf, const int* __restrict__ c0, int n0,
                     float* __restrict__ pm, float* __restrict__ out1) {
  int i = blockIdx.x * 256 + threadIdx.x;
  if (i >= n0) return;
  float b = (float)c0[(size_t)i * 4];
  float x = vf[(size_t)i * 4], y = vf[(size_t)i * 4 + 1], z = vf[(size_t)i * 4 + 2];
  pm[(size_t)i * 4] = b; pm[(size_t)i * 4 + 1] = x; pm[(size_t)i * 4 + 2] = y; pm[(size_t)i * 4 + 3] = z;
  out1[(size_t)i * 4] = b; out1[(size_t)i * 4 + 1] = x; out1[(size_t)i * 4 + 2] = y; out1[(size_t)i * 4 + 3] = z;
}

// ---------------- knn prep ----------------
__global__ void knnprep_k(const int* __restrict__ coords, int nl, float vx, float vy, float vz,
                          float4* __restrict__ kp4, int* __restrict__ bs) {
  int i = blockIdx.x * 256 + threadIdx.x;
  if (i >= nl) return;
  const int* c = coords + (size_t)i * 4;
  kp4[i] = make_float4(OFFX + (c[3] + 0.5f) * vx,
                       OFFY + (c[2] + 0.5f) * vy,
                       OFFZ + (c[1] + 0.5f) * vz, (float)c[0]);
  if (c[0] == 0 && (i + 1 == nl || coords[(size_t)(i + 1) * 4] == 1)) bs[0] = i + 1;
}

// ---------------- 3-NN: z-slab chunk pruning. Candidates z-sorted per batch; each wave
// seeds its bound on its z-home chunk, then chunks with z-gap^2 > wave-min(d2) are skipped
// (safe: every lane d2 >= final d2; dist^2 >= dz^2; strict >). Block-uniform barriers. ----------------
__global__ __launch_bounds__(256) void knn_k(const float4* __restrict__ pm4, int n0,
                                             const float4* __restrict__ kp4, int nl,
                                             const int* __restrict__ bsp,
                                             float* __restrict__ wv, int* __restrict__ iv) {
  __shared__ __align__(16) float4 kp[256];
  __shared__ int bl[4], bh[4], sseed[4], sflag[4];
  int tid = threadIdx.x;
  int wave = tid >> 6, lane = tid & 63;
  int u = blockIdx.x * 4 + wave;
  bool valid = u < n0;
  float4 up = pm4[valid ? u : (n0 - 1)];
  int bs = bsp[0];
  int lo = (up.x == 0.f) ? 0 : bs;
  int hi = (up.x == 0.f) ? bs : nl;
  if (!valid) { lo = 0; hi = 0; }
  if (lane == 0) { bl[wave] = valid ? lo : 0x7fffffff; bh[wave] = valid ? hi : 0; }
  __syncthreads();
  int blo = min(min(bl[0], bl[1]), min(bl[2], bl[3]));
  int bhi = max(max(bh[0], bh[1]), max(bh[2], bh[3]));
  float ux = up.y, uy = up.z, uz = up.w;
  float d0 = 3e38f, d1 = 3e38f, d2 = 3e38f;
  int i0 = -1, i1 = -1, i2 = -1;
  int NT = (bhi > blo) ? ((bhi - blo + 255) >> 8) : 0;

  // wave's z-home chunk (lane-parallel prefix scan; z non-decreasing within batch)
  int pref = -1;
  if (valid) {
    int tfirst = (lo - blo) >> 8;
    int tlast = (hi - 1 - blo) >> 8;
    pref = tfirst;
    for (int base = tfirst + 1; base <= tlast; base += 64) {
      int t2 = base + lane;
      bool okf = false;
      if (t2 <= tlast) {
        int cs = blo + (t2 << 8);
        okf = (kp4[cs].z <= uz);
      }
      unsigned long long mask = __ballot(okf);
      if (mask) pref = base + (63 - __builtin_clzll(mask));
    }
  }
  if (lane == 0) sseed[wave] = pref;
  __syncthreads();

#define INS1(DD, GI) { \
    bool l0 = (DD) < d0, l1 = (DD) < d1, l2 = (DD) < d2; \
    i2 = l2 ? (l1 ? i1 : (GI)) : i2; \
    i1 = l1 ? (l0 ? i0 : (GI)) : i1; \
    i0 = l0 ? (GI) : i0; \
    float t1_ = __builtin_amdgcn_fmed3f(d0, d1, (DD)); \
    float t2_ = __builtin_amdgcn_fmed3f(d1, d2, (DD)); \
    d0 = fminf(d0, (DD)); d1 = t1_; d2 = t2_; }
#define DIST(Q) fmaf(ux - (Q).x, ux - (Q).x, fmaf(uy - (Q).y, uy - (Q).y, (uz - (Q).z) * (uz - (Q).z)))
#define PROC_CHUNK(CB, M) { \
    if (!((CB) + 256 <= lo || (CB) >= hi)) { \
      if ((M) == 256 && (CB) >= lo && (CB) + 256 <= hi) { \
        float4 q0 = kp[lane], q1 = kp[lane + 64], q2 = kp[lane + 128], q3 = kp[lane + 192]; \
        float a0 = DIST(q0), a1 = DIST(q1), a2 = DIST(q2), a3 = DIST(q3); \
        INS1(a0, (CB) + lane) INS1(a1, (CB) + lane + 64) \
        INS1(a2, (CB) + lane + 128) INS1(a3, (CB) + lane + 192) \
      } else { \
        for (int j = 0; j < 4; j++) { \
          int ii = lane + 64 * j; \
          int e = (CB) + ii; \
          if (ii < (M) && e >= lo && e < hi) { \
            float4 q = kp[ii]; \
            float dd = DIST(q); \
            INS1(dd, e) \
          } \
        } \
      } \
    } }

  // Phase A: seed chunks (block-uniform, deduped)
  for (int w = 0; w < 4; w++) {
    int t2 = sseed[w];
    bool skip = (t2 < 0);
    for (int w2 = 0; w2 < w; w2++) if (sseed[w2] == t2) skip = true;
    if (skip) continue;
    int cb = blo + (t2 << 8);
    int m = bhi - cb; if (m > 256) m = 256;
    __syncthreads();
    if (tid < m) kp[tid] = kp4[cb + tid];
    __syncthreads();
    PROC_CHUNK(cb, m)
  }

  // Phase B: sweep remaining chunks with z-gap pruning
  for (int t2 = 0; t2 < NT; t2++) {
    if (t2 == sseed[0] || t2 == sseed[1] || t2 == sseed[2] || t2 == sseed[3]) continue;
    int cb = blo + (t2 << 8);
    int m = bhi - cb; if (m > 256) m = 256;
    bool skipw = true;
    int s0 = cb > lo ? cb : lo;
    int s1 = (cb + m < hi) ? cb + m : hi;
    if (valid && s0 < s1) {
      float zl = kp4[s0].z;
      float zh = kp4[s1 - 1].z;
      float dz = (uz < zl) ? (zl - uz) : ((uz > zh) ? (uz - zh) : 0.f);
      float wb = d2;
#pragma unroll
      for (int off = 32; off; off >>= 1) wb = fminf(wb, __shfl_xor(wb, off));
      skipw = (dz * dz > wb);
    }
    if (lane == 0) sflag[wave] = skipw ? 1 : 0;
    __syncthreads();
    bool allskip = sflag[0] && sflag[1] && sflag[2] && sflag[3];
    if (!allskip) { if (tid < m) kp[tid] = kp4[cb + tid]; }
    __syncthreads();
    if (allskip || skipw) continue;
    PROC_CHUNK(cb, m)
  }

  // butterfly merge of 64 local top-3 triples
#pragma unroll
  for (int off = 1; off < 64; off <<= 1) {
    float e0 = __shfl_xor(d0, off), e1 = __shfl_xor(d1, off), e2 = __shfl_xor(d2, off);
    int j0 = __shfl_xor(i0, off), j1 = __shfl_xor(i1, off), j2 = __shfl_xor(i2, off);
    INS1(e0, j0) INS1(e1, j1) INS1(e2, j2)
  }
#undef PROC_CHUNK
#undef DIST
#undef INS1
  if (valid && lane == 0) {
    float w0 = 1.f / (d0 + 1e-8f), w1 = 1.f / (d1 + 1e-8f), w2 = 1.f / (d2 + 1e-8f);
    float s = w0 + w1 + w2;
    wv[(size_t)u * 3] = w0 / s; wv[(size_t)u * 3 + 1] = w1 / s; wv[(size_t)u * 3 + 2] = w2 / s;
    iv[(size_t)u * 3] = i0; iv[(size_t)u * 3 + 1] = i1; iv[(size_t)u * 3 + 2] = i2;
  }
}

// interp with fused BN+ReLU, reading h2 pre-activations
__global__ void interp_k(const unsigned* __restrict__ fh, int C, const float* __restrict__ scsh,
                         const float* __restrict__ wv, const int* __restrict__ iv, int n0,
                         float* __restrict__ X, int xoff) {
  int t = blockIdx.x * 256 + threadIdx.x;
  if (t >= n0 * C) return;
  int u = t / C, c = t % C;
  int cp = c >> 1, sel = c & 1;
  int CP = C >> 1;
  float sc = scsh[c], sh = scsh[C + c];
  h2_t h0 = u2h(fh[(size_t)iv[(size_t)u * 3]     * CP + cp]);
  h2_t h1 = u2h(fh[(size_t)iv[(size_t)u * 3 + 1] * CP + cp]);
  h2_t h2v = u2h(fh[(size_t)iv[(size_t)u * 3 + 2] * CP + cp]);
  float a0 = fmaxf(fmaf((float)h0[sel], sc, sh), 0.f);
  float a1 = fmaxf(fmaf((float)h1[sel], sc, sh), 0.f);
  float a2 = fmaxf(fmaf((float)h2v[sel], sc, sh), 0.f);
  X[(size_t)u * 160 + xoff + c] = wv[(size_t)u * 3] * a0 + wv[(size_t)u * 3 + 1] * a1
                                + wv[(size_t)u * 3 + 2] * a2;
}

// ---------------- extra 1x1 conv, h2 input with fused BN ----------------
__global__ __launch_bounds__(256) void conv1x1_k(const unsigned* __restrict__ fh,
                                                 const float* __restrict__ scsh,
                                                 const float* __restrict__ we, int n,
                                                 float* __restrict__ out) {
  __shared__ float rows[256];
  int t = threadIdx.x;
  int p = blockIdx.x * 4 + (t >> 6), c = t & 63;
  float v = 0.f;
  if (p < n) {
    h2_t h = u2h(fh[(size_t)p * 32 + (c >> 1)]);
    v = fmaxf(fmaf((float)h[c & 1], scsh[c], scsh[64 + c]), 0.f);
  }
  rows[t] = v;
  __syncthreads();
  if (p >= n) return;
  const float* fr = rows + (t >> 6) * 64;
  float a = 0.f;
#pragma unroll 16
  for (int ci = 0; ci < 64; ci++) a = fmaf(fr[ci], we[ci * 64 + c], a);
  out[(size_t)p * 64 + c] = a;
}

// ---------------- dense scatter with fused BN+ReLU ----------------
__global__ void scatter_k(const float* __restrict__ pre, const float* __restrict__ scsh,
                          const int* __restrict__ c3, int n3, float* __restrict__ out0) {
  int t = blockIdx.x * 256 + threadIdx.x;
  if (t >= n3 * 64) return;
  int p = t >> 6, c = t & 63;
  const int* cc = c3 + (size_t)p * 4;
  size_t o = ((((size_t)cc[0] * 64 + c) * 6 + cc[1]) * 100 + cc[2]) * 100 + cc[3];
  out0[o] = fmaxf(fmaf(pre[t], scsh[c], scsh[64 + c]), 0.f);
}

// ---------------- head ----------------
__global__ __launch_bounds__(256) void head_k(const float* __restrict__ X,
                                              const float* __restrict__ fcw,
                                              const float* __restrict__ clsw,
                                              const float* __restrict__ regw,
                                              int n0, float* __restrict__ outc,
                                              float* __restrict__ outr) {
  __shared__ float fl[64 * 161];
  int t = threadIdx.x;
  for (int i = t; i < 64 * 160; i += 256) {
    int r = i / 160, c = i % 160;
    fl[r * 161 + c] = fcw[i];
  }
  __syncthreads();
  int wave = t >> 6, lane = t & 63;
  int u = blockIdx.x * 4 + wave;
  if (u >= n0) return;
  const float* xr = X + (size_t)u * 160;
  const float* wr = fl + (size_t)lane * 161;
  float a = 0.f;
#pragma unroll 8
  for (int i = 0; i < 160; i++) a = fmaf(xr[i], wr[i], a);
  float c = a * clsw[lane];
  float r0 = a * regw[lane], r1 = a * regw[64 + lane], r2 = a * regw[128 + lane];
  for (int off = 32; off; off >>= 1) {
    c  += __shfl_down(c, off);
    r0 += __shfl_down(r0, off);
    r1 += __shfl_down(r1, off);
    r2 += __shfl_down(r2, off);
  }
  if (lane == 0) {
    outc[u] = c;
    outr[(size_t)u * 3] = r0; outr[(size_t)u * 3 + 1] = r1; outr[(size_t)u * 3 + 2] = r2;
  }
}

// ---------------- host ----------------
extern "C" void kernel_launch(void* const* d_in, const int* in_sizes, int n_in,
                              void* d_out, int out_size, void* d_ws, size_t ws_size,
                              hipStream_t stream) {
  const float* vf  = (const float*)d_in[0];
  const int* c0 = (const int*)d_in[1];
  const int* c1 = (const int*)d_in[2];
  const int* c2 = (const int*)d_in[3];
  const int* c3 = (const int*)d_in[4];
  const float* w00 = (const float*)d_in[5];  const float* b00 = (const float*)d_in[6];
  const float* w01 = (const float*)d_in[7];  const float* b01 = (const float*)d_in[8];
  const float* wd0 = (const float*)d_in[9];  const float* bd0 = (const float*)d_in[10];
  const float* w10 = (const float*)d_in[11]; const float* b10 = (const float*)d_in[12];
  const float* w11 = (const float*)d_in[13]; const float* b11 = (const float*)d_in[14];
  const float* wd1 = (const float*)d_in[15]; const float* bd1 = (const float*)d_in[16];
  const float* w20 = (const float*)d_in[17]; const float* b20 = (const float*)d_in[18];
  const float* w21 = (const float*)d_in[19]; const float* b21 = (const float*)d_in[20];
  const float* w22 = (const float*)d_in[21]; const float* b22 = (const float*)d_in[22];
  const float* wd2 = (const float*)d_in[23]; const float* bd2 = (const float*)d_in[24];
  const float* w30 = (const float*)d_in[25]; const float* b30 = (const float*)d_in[26];
  const float* w31 = (const float*)d_in[27]; const float* b31 = (const float*)d_in[28];
  const float* w32 = (const float*)d_in[29]; const float* b32 = (const float*)d_in[30];
  const float* we  = (const float*)d_in[31]; const float* be  = (const float*)d_in[32];
  const float* fcw = (const float*)d_in[33];
  const float* clsw = (const float*)d_in[34];
  const float* regw = (const float*)d_in[35];

  int N0 = in_sizes[1] / 4, N1 = in_sizes[2] / 4, N2 = in_sizes[3] / 4, N3 = in_sizes[4] / 4;
  int maxN = N0; if (N1 > maxN) maxN = N1; if (N2 > maxN) maxN = N2; if (N3 > maxN) maxN = N3;

  auto cdiv = [](int a, int b) { return (a + b - 1) / b; };
  char* p = (char*)d_ws;
  auto alloc = [&](size_t bytes) { char* r = p; p += (bytes + 255) & ~(size_t)255; return r; };

  int* keys0 = (int*)alloc((size_t)N0 * 4);
  int* keys1 = (int*)alloc((size_t)N1 * 4);
  int* keys2 = (int*)alloc((size_t)N2 * 4);
  int* keys3 = (int*)alloc((size_t)N3 * 4);
  int* nbr0  = (int*)alloc((size_t)N0 * 27 * 4);
  int* nbrs1 = (int*)alloc((size_t)N1 * 27 * 4);
  int* nbr1  = (int*)alloc((size_t)N1 * 27 * 4);
  int* nbrs2 = (int*)alloc((size_t)N2 * 27 * 4);
  int* nbr2  = (int*)alloc((size_t)N2 * 27 * 4);
  int* nbrs3 = (int*)alloc((size_t)N3 * 27 * 4);
  int* nbr3  = (int*)alloc((size_t)N3 * 27 * 4);
  float* FA = (float*)alloc((size_t)maxN * 64 * 4);
  float* FB = (float*)alloc((size_t)maxN * 64 * 4);
  float* FC = (float*)alloc((size_t)maxN * 64 * 4);
  unsigned* FAh = (unsigned*)alloc((size_t)maxN * 32 * 4);
  unsigned* FBh = (unsigned*)alloc((size_t)maxN * 32 * 4);
  float* stats = (float*)alloc((size_t)NCH * 64 * 2 * 4);
  float* SC = (float*)alloc((size_t)15 * 128 * 4);
  int* ctrs = (int*)alloc(16 * 4);
  float* wv = (float*)alloc((size_t)N0 * 3 * 4);
  int*   iv = (int*)alloc((size_t)N0 * 3 * 4);
  float* X  = (float*)alloc((size_t)N0 * 160 * 4);
  float* pmb = (float*)alloc((size_t)N0 * 4 * 4);
  float4* kp1 = (float4*)alloc((size_t)N1 * 16);
  float4* kp2 = (float4*)alloc((size_t)N2 * 16);
  float4* kp3 = (float4*)alloc((size_t)N3 * 16);
  int* bsA = (int*)alloc(32);
  unsigned* whbuf = (unsigned*)alloc((size_t)452736 * 4);

  float* out0 = (float*)d_out;
  float* out1 = out0 + 7680000;
  float* outc = out1 + (size_t)N0 * 4;
  float* outr = outc + N0;
  float* partial = out0;  // conv partial scratch until final memset

  auto scsh = [&](int L) { return SC + (size_t)L * 128; };

  const float* wsrc[13] = {w01, wd0, w10, w11, wd1, w20, w21, w22, wd2, w30, w31, w32, nullptr};
  int wcin[13]  = {16, 16, 32, 32, 32, 64, 64, 64, 64, 64, 64, 64, 0};
  int wcout[13] = {16, 32, 32, 32, 64, 64, 64, 64, 64, 64, 64, 64, 0};
  unsigned* wdst[13];
  size_t woff = 0;
  WP13 wp{};
  int nw = 12;
  for (int i = 0; i < nw; i++) {
    wdst[i] = whbuf + woff;
    wp.l[i] = WPrep{wsrc[i], wdst[i], wcin[i], wcout[i]};
    woff += (size_t)27 * (wcin[i] / 2) * wcout[i];
  }
  for (int i = nw; i < 13; i++) wp.l[i] = WPrep{w01, wdst[0], 16, 16};

  hipMemsetAsync(ctrs, 0, 16 * 4, stream);
  wprep_k<<<dim3(216, nw), 256, 0, stream>>>(wp);
  keys_k<<<cdiv(N0, 256), 256, 0, stream>>>(c0, N0, 41, 800, 800, keys0);
  keys_k<<<cdiv(N1, 256), 256, 0, stream>>>(c1, N1, 21, 400, 400, keys1);
  keys_k<<<cdiv(N2, 256), 256, 0, stream>>>(c2, N2, 11, 200, 200, keys2);
  keys_k<<<cdiv(N3, 256), 256, 0, stream>>>(c3, N3, 6, 100, 100, keys3);
  nbr_k<<<cdiv(N0 * 27, 256), 256, 0, stream>>>(c0, N0, keys0, N0, 41, 800, 800, 1, nbr0);
  nbr_k<<<cdiv(N1 * 27, 256), 256, 0, stream>>>(c1, N1, keys0, N0, 41, 800, 800, 2, nbrs1);
  nbr_k<<<cdiv(N1 * 27, 256), 256, 0, stream>>>(c1, N1, keys1, N1, 21, 400, 400, 1, nbr1);
  nbr_k<<<cdiv(N2 * 27, 256), 256, 0, stream>>>(c2, N2, keys1, N1, 21, 400, 400, 2, nbrs2);
  nbr_k<<<cdiv(N2 * 27, 256), 256, 0, stream>>>(c2, N2, keys2, N2, 11, 200, 200, 1, nbr2);
  nbr_k<<<cdiv(N3 * 27, 256), 256, 0, stream>>>(c3, N3, keys2, N2, 11, 200, 200, 2, nbrs3);
  nbr_k<<<cdiv(N3 * 27, 256), 256, 0, stream>>>(c3, N3, keys3, N3, 6, 100, 100, 1, nbr3);
  pm_k<<<cdiv(N0, 256), 256, 0, stream>>>(vf, c0, N0, pmb, out1);
  knnprep_k<<<cdiv(N1, 256), 256, 0, stream>>>(c1, N1, 0.2f, 0.2f, 0.4f, kp1, bsA + 0);
  knnprep_k<<<cdiv(N2, 256), 256, 0, stream>>>(c2, N2, 0.4f, 0.4f, 0.8f, kp2, bsA + 1);
  knnprep_k<<<cdiv(N3, 256), 256, 0, stream>>>(c3, N3, 0.8f, 0.8f, 1.6f, kp3, bsA + 2);

  auto convh = [&](const unsigned* fhin, const int* nb, int wi, int n, int cin, int cout,
                   const float* ss) {
    dim3 g(cdiv(n, 32), NG);
    int gs = n * cout;
    const unsigned* wh = wdst[wi];
    if (cin == 16 && cout == 16)
      convh_k<16, 16><<<g, 128, 0, stream>>>(fhin, nb, wh, n, partial, gs, ss);
    else if (cin == 16 && cout == 32)
      convh_k<16, 32><<<g, 128, 0, stream>>>(fhin, nb, wh, n, partial, gs, ss);
    else if (cin == 32 && cout == 32)
      convh_k<32, 32><<<g, 128, 0, stream>>>(fhin, nb, wh, n, partial, gs, ss);
    else if (cin == 32 && cout == 64)
      convh_k<32, 64><<<g, 128, 0, stream>>>(fhin, nb, wh, n, partial, gs, ss);
    else
      convh_k<64, 64><<<g, 128, 0, stream>>>(fhin, nb, wh, n, partial, gs, ss);
  };
  auto bnp = [&](const float* bnpar, int n, int C, float* pre, unsigned* preh, int L) {
    bn_k<<<NCH, 256, 0, stream>>>(partial, NG, n * C, n, C, pre, preh, stats, bnpar,
                                  scsh(L), ctrs + L);
  };
  auto knn = [&](const float4* kp4, const int* bsl, int nl, const unsigned* fh, int C, int L,
                 int xoff) {
    knn_k<<<cdiv(N0, 4), 256, 0, stream>>>((const float4*)pmb, N0, kp4, nl, bsl, wv, iv);
    interp_k<<<cdiv(N0 * C, 256), 256, 0, stream>>>(fh, C, scsh(L), wv, iv, N0, X, xoff);
  };

  // layer 0: fp32 conv from raw voxel features
  convg_k<4, 16><<<dim3(cdiv(N0, 32), NG), 128, 0, stream>>>(vf, nbr0, w00, N0, partial, N0 * 16);
  bnp(b00, N0, 16, nullptr, FAh, 0);
  convh(FAh, nbr0, 0, N0, 16, 16, scsh(0));   bnp(b01, N0, 16, nullptr, FBh, 1);
  convh(FBh, nbrs1, 1, N1, 16, 32, scsh(1));  bnp(bd0, N1, 32, nullptr, FAh, 2);
  convh(FAh, nbr1, 2, N1, 32, 32, scsh(2));   bnp(b10, N1, 32, nullptr, FBh, 3);
  convh(FBh, nbr1, 3, N1, 32, 32, scsh(3));   bnp(b11, N1, 32, nullptr, FAh, 4);
  knn(kp1, bsA + 0, N1, FAh, 32, 4, 0);
  convh(FAh, nbrs2, 4, N2, 32, 64, scsh(4));  bnp(bd1, N2, 64, nullptr, FBh, 5);
  convh(FBh, nbr2, 5, N2, 64, 64, scsh(5));   bnp(b20, N2, 64, nullptr, FAh, 6);
  convh(FAh, nbr2, 6, N2, 64, 64, scsh(6));   bnp(b21, N2, 64, nullptr, FBh, 7);
  convh(FBh, nbr2, 7, N2, 64, 64, scsh(7));   bnp(b22, N2, 64, nullptr, FAh, 8);
  knn(kp2, bsA + 1, N2, FAh, 64, 8, 32);
  convh(FAh, nbrs3, 8, N3, 64, 64, scsh(8));  bnp(bd2, N3, 64, nullptr, FBh, 9);
  convh(FBh, nbr3, 9, N3, 64, 64, scsh(9));   bnp(b30, N3, 64, nullptr, FAh, 10);
  convh(FAh, nbr3, 10, N3, 64, 64, scsh(10)); bnp(b31, N3, 64, nullptr, FBh, 11);
  convh(FBh, nbr3, 11, N3, 64, 64, scsh(11)); bnp(b32, N3, 64, nullptr, FAh, 12);
  knn(kp3, bsA + 2, N3, FAh, 64, 12, 96);

  conv1x1_k<<<cdiv(N3, 4), 256, 0, stream>>>(FAh, scsh(12), we, N3, FC);
  bn_k<<<NCH, 256, 0, stream>>>(FC, 1, 0, N3, 64, FB, FBh, stats, be, scsh(13), ctrs + 13);
  hipMemsetAsync(d_out, 0, (size_t)7680000 * 4, stream);
  scatter_k<<<cdiv(N3 * 64, 256), 256, 0, stream>>>(FB, scsh(13), c3, N3, out0);
  head_k<<<cdiv(N0, 4), 256, 0, stream>>>(X, fcw, clsw, regw, N0, outc, outr);
}

// Round 17
// 931.160 us; speedup vs baseline: 1.0565x; 1.0565x over previous
//
#include <hip/hip_runtime.h>

#define OFFX 0.0f
#define OFFY -40.0f
#define OFFZ -3.0f
#define BNEPS 1e-3f
#define NCH 128   // bn partial chunks
#define NG 9      // conv tap groups (3 taps each)

typedef _Float16 h2_t __attribute__((ext_vector_type(2)));
__device__ inline h2_t u2h(unsigned u) { union { unsigned u; h2_t h; } x; x.u = u; return x.h; }
__device__ inline unsigned h2u(h2_t h) { union { unsigned u; h2_t h; } x; x.h = h; return x.u; }

// ---------------- keys ----------------
__global__ void keys_k(const int* __restrict__ coords, int n, int D, int H, int W,
                       int* __restrict__ keys) {
  int i = blockIdx.x * 256 + threadIdx.x;
  if (i < n) {
    const int* c = coords + (size_t)i * 4;
    keys[i] = ((c[0] * D + c[1]) * H + c[2]) * W + c[3];
  }
}

// ---------------- neighbor tables ----------------
__global__ void nbr_k(const int* __restrict__ coords, int np, const int* __restrict__ keys, int nk,
                      int D, int H, int W, int scale, int* __restrict__ nbr) {
  int t = blockIdx.x * 256 + threadIdx.x;
  if (t >= np * 27) return;
  int p = t / 27, k = t % 27;
  int kz = k / 9 - 1, ky = (k / 3) % 3 - 1, kx = k % 3 - 1;
  const int* c = coords + (size_t)p * 4;
  int z = c[1] * scale + kz, y = c[2] * scale + ky, x = c[3] * scale + kx;
  int r = -1;
  if (z >= 0 && z < D && y >= 0 && y < H && x >= 0 && x < W) {
    int q = ((c[0] * D + z) * H + y) * W + x;
    int lo = 0, hi = nk;
    while (lo < hi) { int m = (lo + hi) >> 1; if (keys[m] < q) lo = m + 1; else hi = m; }
    if (lo < nk && keys[lo] == q) r = lo;
  }
  nbr[t] = r;
}

// ---------------- weight prep: fp32 [27][CIN][COUT] -> h2 [27][CIN/2][COUT] ----------------
struct WPrep { const float* src; unsigned* dst; int cin; int cout; };
struct WP13 { WPrep l[13]; };
__global__ void wprep_k(WP13 a) {
  WPrep w = a.l[blockIdx.y];
  int cp2 = w.cin / 2;
  int tot = 27 * cp2 * w.cout;
  int i = blockIdx.x * 256 + threadIdx.x;
  if (i >= tot) return;
  int o = i % w.cout, rest = i / w.cout;
  int cp = rest % cp2, k = rest / cp2;
  float lo = w.src[((size_t)k * w.cin + 2 * cp) * w.cout + o];
  float hi = w.src[((size_t)k * w.cin + 2 * cp + 1) * w.cout + o];
  h2_t h; h[0] = (_Float16)lo; h[1] = (_Float16)hi;
  w.dst[i] = h2u(h);
}

// ---------------- layer-0 conv (fp32, CIN=4): LDS tile-GEMM TP=32 ----------------
template<int CIN, int COUT>
__global__ __launch_bounds__(128) void convg_k(const float* __restrict__ feats,
                                               const int* __restrict__ nbr,
                                               const float* __restrict__ w, int n,
                                               float* __restrict__ partial, int gstride) {
  constexpr int TP = 32;
  constexpr int LDP = 36;
  constexpr int CO = COUT / 16;
  __shared__ float G[CIN * LDP];
  int tid = threadIdx.x;
  int pg = tid >> 4, cg = tid & 15;
  int p0 = blockIdx.x * TP;
  int k0 = blockIdx.y * 3;
  float acc[4][CO];
#pragma unroll
  for (int i = 0; i < 4; i++)
#pragma unroll
    for (int j = 0; j < CO; j++) acc[i][j] = 0.f;

  for (int kk = 0; kk < 3; kk++) {
    int k = k0 + kk;
    __syncthreads();
    for (int ch = tid; ch < TP * CIN / 4; ch += 128) {
      int r = ch & (TP - 1), c4 = ch / TP;
      int p = p0 + r;
      int idx = (p < n) ? nbr[(size_t)p * 27 + k] : -1;
      float4 fv = make_float4(0.f, 0.f, 0.f, 0.f);
      if (idx >= 0) fv = *(const float4*)(feats + (size_t)idx * CIN + c4 * 4);
      G[(c4 * 4 + 0) * LDP + r] = fv.x;
      G[(c4 * 4 + 1) * LDP + r] = fv.y;
      G[(c4 * 4 + 2) * LDP + r] = fv.z;
      G[(c4 * 4 + 3) * LDP + r] = fv.w;
    }
    __syncthreads();
    const float* wk = w + (size_t)k * CIN * COUT + cg * CO;
#pragma unroll
    for (int c = 0; c < CIN; c++) {
      float4 g4 = *(const float4*)&G[c * LDP + pg * 4];
      float wv[CO];
      if constexpr (CO == 4)      *(float4*)wv = *(const float4*)(wk + c * COUT);
      else if constexpr (CO == 2) *(float2*)wv = *(const float2*)(wk + c * COUT);
      else                        wv[0] = wk[c * COUT];
      float gp[4] = {g4.x, g4.y, g4.z, g4.w};
#pragma unroll
      for (int i = 0; i < 4; i++)
#pragma unroll
        for (int j = 0; j < CO; j++) acc[i][j] = fmaf(gp[i], wv[j], acc[i][j]);
    }
  }
#pragma unroll
  for (int i = 0; i < 4; i++) {
    int p = p0 + pg * 4 + i;
    if (p < n) {
      float* dst = partial + (size_t)blockIdx.y * gstride + (size_t)p * COUT + cg * CO;
      if constexpr (CO == 4)      *(float4*)dst = *(float4*)acc[i];
      else if constexpr (CO == 2) *(float2*)dst = *(float2*)acc[i];
      else                        dst[0] = acc[i][0];
    }
  }
}

// ---------------- f16 conv: software-pipelined gather, fdot2, fused BN+ReLU ----------------
template<int CIN, int COUT>
__global__ __launch_bounds__(128) void convh_k(const unsigned* __restrict__ fh,
                                               const int* __restrict__ nbr,
                                               const unsigned* __restrict__ wh, int n,
                                               float* __restrict__ partial, int gstride,
                                               const float* __restrict__ scsh) {
  constexpr int TP = 32;
  constexpr int LDPH = 36;
  constexpr int CO = COUT / 16;
  constexpr int CP = CIN / 2;
  __shared__ unsigned H[CP * LDPH];
  int tid = threadIdx.x;
  int pg = tid >> 4, cg = tid & 15;
  int p0 = blockIdx.x * TP;
  int k0 = blockIdx.y * 3;
  int r = tid & 31;
  int p = p0 + r;
  int sidx[3];
  if (p < n) {
    const int* nb = nbr + (size_t)p * 27 + k0;
    sidx[0] = nb[0]; sidx[1] = nb[1]; sidx[2] = nb[2];
  } else { sidx[0] = sidx[1] = sidx[2] = -1; }

  float acc[4][CO];
#pragma unroll
  for (int i = 0; i < 4; i++)
#pragma unroll
    for (int j = 0; j < CO; j++) acc[i][j] = 0.f;

  if constexpr (CIN >= 32) {
    constexpr int NLD = CIN / 32;
    uint4 pf[NLD];
    {
      int idx = sidx[0];
#pragma unroll
      for (int it = 0; it < NLD; it++) {
        int q = (tid >> 5) + it * 4;
        pf[it] = (idx >= 0) ? *(const uint4*)(fh + (size_t)idx * CP + q * 4)
                            : make_uint4(0, 0, 0, 0);
      }
    }
    for (int kk = 0; kk < 3; kk++) {
      bool ok = sidx[kk] >= 0;
      __syncthreads();
#pragma unroll
      for (int it = 0; it < NLD; it++) {
        int q = (tid >> 5) + it * 4;
        unsigned uu[4] = {pf[it].x, pf[it].y, pf[it].z, pf[it].w};
#pragma unroll
        for (int j = 0; j < 4; j++) {
          int cp = q * 4 + j;
          unsigned outw = 0;
          if (ok) {
            h2_t h = u2h(uu[j]);
            float lo = fmaxf(fmaf((float)h[0], scsh[2 * cp], scsh[CIN + 2 * cp]), 0.f);
            float hi = fmaxf(fmaf((float)h[1], scsh[2 * cp + 1], scsh[CIN + 2 * cp + 1]), 0.f);
            h2_t o; o[0] = (_Float16)lo; o[1] = (_Float16)hi;
            outw = h2u(o);
          }
          H[cp * LDPH + r] = outw;
        }
      }
      if (kk < 2) {
        int idx = sidx[kk + 1];
#pragma unroll
        for (int it = 0; it < NLD; it++) {
          int q = (tid >> 5) + it * 4;
          pf[it] = (idx >= 0) ? *(const uint4*)(fh + (size_t)idx * CP + q * 4)
                              : make_uint4(0, 0, 0, 0);
        }
      }
      __syncthreads();
      const unsigned* wk = wh + (size_t)(k0 + kk) * CP * COUT + cg * CO;
#pragma unroll 8
      for (int cp = 0; cp < CP; cp++) {
        uint4 g4 = *(const uint4*)&H[cp * LDPH + pg * 4];
        unsigned gg[4] = {g4.x, g4.y, g4.z, g4.w};
        unsigned wv[CO];
        if constexpr (CO == 4)      *(uint4*)wv = *(const uint4*)(wk + cp * COUT);
        else if constexpr (CO == 2) *(uint2*)wv = *(const uint2*)(wk + cp * COUT);
        else                        wv[0] = wk[cp * COUT];
#pragma unroll
        for (int i = 0; i < 4; i++)
#pragma unroll
          for (int j = 0; j < CO; j++)
            acc[i][j] = __builtin_amdgcn_fdot2(u2h(gg[i]), u2h(wv[j]), acc[i][j], false);
      }
    }
  } else {  // CIN == 16
    int q = tid >> 5;
    uint2 pf2;
    {
      int idx = sidx[0];
      pf2 = (idx >= 0) ? *(const uint2*)(fh + (size_t)idx * CP + q * 2) : make_uint2(0, 0);
    }
    for (int kk = 0; kk < 3; kk++) {
      bool ok = sidx[kk] >= 0;
      __syncthreads();
      unsigned uu[2] = {pf2.x, pf2.y};
#pragma unroll
      for (int j = 0; j < 2; j++) {
        int cp = q * 2 + j;
        unsigned outw = 0;
        if (ok) {
          h2_t h = u2h(uu[j]);
          float lo = fmaxf(fmaf((float)h[0], scsh[2 * cp], scsh[CIN + 2 * cp]), 0.f);
          float hi = fmaxf(fmaf((float)h[1], scsh[2 * cp + 1], scsh[CIN + 2 * cp + 1]), 0.f);
          h2_t o; o[0] = (_Float16)lo; o[1] = (_Float16)hi;
          outw = h2u(o);
        }
        H[cp * LDPH + r] = outw;
      }
      if (kk < 2) {
        int idx = sidx[kk + 1];
        pf2 = (idx >= 0) ? *(const uint2*)(fh + (size_t)idx * CP + q * 2) : make_uint2(0, 0);
      }
      __syncthreads();
      const unsigned* wk = wh + (size_t)(k0 + kk) * CP * COUT + cg * CO;
#pragma unroll
      for (int cp = 0; cp < CP; cp++) {
        uint4 g4 = *(const uint4*)&H[cp * LDPH + pg * 4];
        unsigned gg[4] = {g4.x, g4.y, g4.z, g4.w};
        unsigned wv[CO];
        if constexpr (CO == 4)      *(uint4*)wv = *(const uint4*)(wk + cp * COUT);
        else if constexpr (CO == 2) *(uint2*)wv = *(const uint2*)(wk + cp * COUT);
        else                        wv[0] = wk[cp * COUT];
#pragma unroll
        for (int i = 0; i < 4; i++)
#pragma unroll
          for (int j = 0; j < CO; j++)
            acc[i][j] = __builtin_amdgcn_fdot2(u2h(gg[i]), u2h(wv[j]), acc[i][j], false);
      }
    }
  }
#pragma unroll
  for (int i = 0; i < 4; i++) {
    int pp = p0 + pg * 4 + i;
    if (pp < n) {
      float* dst = partial + (size_t)blockIdx.y * gstride + (size_t)pp * COUT + cg * CO;
      if constexpr (CO == 4)      *(float4*)dst = *(float4*)acc[i];
      else if constexpr (CO == 2) *(float2*)dst = *(float2*)acc[i];
      else                        dst[0] = acc[i][0];
    }
  }
}

// ---------------- bn: sum partials -> pre(opt fp32) + preh (h2) + stats; last block -> (sc, sh) ----------------
__global__ void bn_k(const float* __restrict__ partial, int G, int gstride, int n, int C,
                     float* __restrict__ pre, unsigned* __restrict__ preh,
                     float* __restrict__ stats, const float* __restrict__ bnp,
                     float* __restrict__ scsh, int* __restrict__ ctr) {
  __shared__ float l1e[256], l2e[256], l1o[256], l2o[256];
  __shared__ int lastf;
  int t = threadIdx.x;
  int total = n * C;
  float s1e = 0.f, s2e = 0.f, s1o = 0.f, s2o = 0.f;
  for (int i2 = (blockIdx.x * 256 + t) * 2; i2 < total; i2 += NCH * 512) {
    float v0 = 0.f, v1 = 0.f;
    for (int g = 0; g < G; g++) {
      float2 pv = *(const float2*)(partial + (size_t)g * gstride + i2);
      v0 += pv.x; v1 += pv.y;
    }
    if (pre) *(float2*)(pre + i2) = make_float2(v0, v1);
    h2_t h; h[0] = (_Float16)v0; h[1] = (_Float16)v1;
    preh[i2 >> 1] = h2u(h);
    s1e += v0; s2e += v0 * v0; s1o += v1; s2o += v1 * v1;
  }
  l1e[t] = s1e; l2e[t] = s2e; l1o[t] = s1o; l2o[t] = s2o;
  for (int s = 128; s >= C / 2; s >>= 1) {
    __syncthreads();
    if (t < s) {
      l1e[t] += l1e[t + s]; l2e[t] += l2e[t + s];
      l1o[t] += l1o[t + s]; l2o[t] += l2o[t + s];
    }
  }
  __syncthreads();
  if (t < C / 2) {
    stats[((size_t)blockIdx.x * C + 2 * t) * 2]     = l1e[t];
    stats[((size_t)blockIdx.x * C + 2 * t) * 2 + 1] = l2e[t];
    stats[((size_t)blockIdx.x * C + 2 * t + 1) * 2]     = l1o[t];
    stats[((size_t)blockIdx.x * C + 2 * t + 1) * 2 + 1] = l2o[t];
  }
  __threadfence();
  __syncthreads();
  if (t == 0) lastf = (atomicAdd(ctr, 1) == NCH - 1) ? 1 : 0;
  __syncthreads();
  if (lastf) {
    __threadfence();
    if (t < C) {
      float a1 = 0.f, a2 = 0.f;
      for (int ch = 0; ch < NCH; ch++) {
        a1 += stats[((size_t)ch * C + t) * 2];
        a2 += stats[((size_t)ch * C + t) * 2 + 1];
      }
      float m = a1 / n;
      float v = a2 / n - m * m;
      float sc = bnp[t] / sqrtf(v + BNEPS);
      scsh[t] = sc;
      scsh[C + t] = bnp[C + t] - m * sc;
    }
  }
}

// ---------------- points_mean ----------------
__global__ void pm_k(const float* __restrict__ vf, const int* __restrict__ c0, int n0,
                     float* __restrict__ pm, float* __restrict__ out1) {
  int i = blockIdx.x * 256 + threadIdx.x;
  if (i >= n0) return;
  float b = (float)c0[(size_t)i * 4];
  float x = vf[(size_t)i * 4], y = vf[(size_t)i * 4 + 1], z = vf[(size_t)i * 4 + 2];
  pm[(size_t)i * 4] = b; pm[(size_t)i * 4 + 1] = x; pm[(size_t)i * 4 + 2] = y; pm[(size_t)i * 4 + 3] = z;
  out1[(size_t)i * 4] = b; out1[(size_t)i * 4 + 1] = x; out1[(size_t)i * 4 + 2] = y; out1[(size_t)i * 4 + 3] = z;
}

// ---------------- knn prep ----------------
__global__ void knnprep_k(const int* __restrict__ coords, int nl, float vx, float vy, float vz,
                          float4* __restrict__ kp4, int* __restrict__ bs) {
  int i = blockIdx.x * 256 + threadIdx.x;
  if (i >= nl) return;
  const int* c = coords + (size_t)i * 4;
  kp4[i] = make_float4(OFFX + (c[3] + 0.5f) * vx,
                       OFFY + (c[2] + 0.5f) * vy,
                       OFFZ + (c[1] + 0.5f) * vz, (float)c[0]);
  if (c[0] == 0 && (i + 1 == nl || coords[(size_t)(i + 1) * 4] == 1)) bs[0] = i + 1;
}

// ---------------- 3-NN: 4 waves/block share LDS-staged chunks; wave per unknown;
// wave-uniform __any vote skips the insert block when no lane improves ----------------
__global__ __launch_bounds__(256) void knn_k(const float4* __restrict__ pm4, int n0,
                                             const float4* __restrict__ kp4, int nl,
                                             const int* __restrict__ bsp,
                                             float* __restrict__ wv, int* __restrict__ iv) {
  __shared__ __align__(16) float4 kp[256];
  __shared__ int bl[4], bh[4];
  int tid = threadIdx.x;
  int wave = tid >> 6, lane = tid & 63;
  int u = blockIdx.x * 4 + wave;
  bool valid = u < n0;
  float4 up = pm4[valid ? u : (n0 - 1)];
  int bs = bsp[0];
  int lo = (up.x == 0.f) ? 0 : bs;
  int hi = (up.x == 0.f) ? bs : nl;
  if (!valid) { lo = 0; hi = 0; }
  if (lane == 0) { bl[wave] = valid ? lo : 0x7fffffff; bh[wave] = valid ? hi : 0; }
  __syncthreads();
  int blo = min(min(bl[0], bl[1]), min(bl[2], bl[3]));
  int bhi = max(max(bh[0], bh[1]), max(bh[2], bh[3]));
  float ux = up.y, uy = up.z, uz = up.w;
  float d0 = 3e38f, d1 = 3e38f, d2 = 3e38f;
  int i0 = -1, i1 = -1, i2 = -1;
#define INS1(DD, GI) { \
    bool l0 = (DD) < d0, l1 = (DD) < d1, l2 = (DD) < d2; \
    i2 = l2 ? (l1 ? i1 : (GI)) : i2; \
    i1 = l1 ? (l0 ? i0 : (GI)) : i1; \
    i0 = l0 ? (GI) : i0; \
    float t1_ = __builtin_amdgcn_fmed3f(d0, d1, (DD)); \
    float t2_ = __builtin_amdgcn_fmed3f(d1, d2, (DD)); \
    d0 = fminf(d0, (DD)); d1 = t1_; d2 = t2_; }
#define DIST(Q) fmaf(ux - (Q).x, ux - (Q).x, fmaf(uy - (Q).y, uy - (Q).y, (uz - (Q).z) * (uz - (Q).z)))
  for (int cb = blo; cb < bhi; cb += 256) {
    int m = bhi - cb; if (m > 256) m = 256;
    __syncthreads();
    if (tid < m) kp[tid] = kp4[cb + tid];
    __syncthreads();
    if (cb + 256 <= lo || cb >= hi) continue;
    if (m == 256 && cb >= lo && cb + 256 <= hi) {
      float4 q0 = kp[lane], q1 = kp[lane + 64], q2 = kp[lane + 128], q3 = kp[lane + 192];
      float a0 = DIST(q0), a1 = DIST(q1), a2 = DIST(q2), a3 = DIST(q3);
      // wave-uniform vote -> real s_cbranch; insert block skipped when nobody improves
      if (__any((a0 < d2) | (a1 < d2) | (a2 < d2) | (a3 < d2))) {
        INS1(a0, cb + lane) INS1(a1, cb + lane + 64)
        INS1(a2, cb + lane + 128) INS1(a3, cb + lane + 192)
      }
    } else {
#pragma unroll
      for (int j = 0; j < 4; j++) {
        int i = lane + 64 * j;
        int e = cb + i;
        if (i < m && e >= lo && e < hi) {
          float4 q = kp[i];
          float dd = DIST(q);
          INS1(dd, e)
        }
      }
    }
  }
#pragma unroll
  for (int off = 1; off < 64; off <<= 1) {
    float e0 = __shfl_xor(d0, off), e1 = __shfl_xor(d1, off), e2 = __shfl_xor(d2, off);
    int j0 = __shfl_xor(i0, off), j1 = __shfl_xor(i1, off), j2 = __shfl_xor(i2, off);
    INS1(e0, j0) INS1(e1, j1) INS1(e2, j2)
  }
#undef DIST
#undef INS1
  if (valid && lane == 0) {
    float w0 = 1.f / (d0 + 1e-8f), w1 = 1.f / (d1 + 1e-8f), w2 = 1.f / (d2 + 1e-8f);
    float s = w0 + w1 + w2;
    wv[(size_t)u * 3] = w0 / s; wv[(size_t)u * 3 + 1] = w1 / s; wv[(size_t)u * 3 + 2] = w2 / s;
    iv[(size_t)u * 3] = i0; iv[(size_t)u * 3 + 1] = i1; iv[(size_t)u * 3 + 2] = i2;
  }
}

// interp with fused BN+ReLU, reading h2 pre-activations
__global__ void interp_k(const unsigned* __restrict__ fh, int C, const float* __restrict__ scsh,
                         const float* __restrict__ wv, const int* __restrict__ iv, int n0,
                         float* __restrict__ X, int xoff) {
  int t = blockIdx.x * 256 + threadIdx.x;
  if (t >= n0 * C) return;
  int u = t / C, c = t % C;
  int cp = c >> 1, sel = c & 1;
  int CP = C >> 1;
  float sc = scsh[c], sh = scsh[C + c];
  h2_t h0 = u2h(fh[(size_t)iv[(size_t)u * 3]     * CP + cp]);
  h2_t h1 = u2h(fh[(size_t)iv[(size_t)u * 3 + 1] * CP + cp]);
  h2_t h2v = u2h(fh[(size_t)iv[(size_t)u * 3 + 2] * CP + cp]);
  float a0 = fmaxf(fmaf((float)h0[sel], sc, sh), 0.f);
  float a1 = fmaxf(fmaf((float)h1[sel], sc, sh), 0.f);
  float a2 = fmaxf(fmaf((float)h2v[sel], sc, sh), 0.f);
  X[(size_t)u * 160 + xoff + c] = wv[(size_t)u * 3] * a0 + wv[(size_t)u * 3 + 1] * a1
                                + wv[(size_t)u * 3 + 2] * a2;
}

// ---------------- extra 1x1 conv, h2 input with fused BN ----------------
__global__ __launch_bounds__(256) void conv1x1_k(const unsigned* __restrict__ fh,
                                                 const float* __restrict__ scsh,
                                                 const float* __restrict__ we, int n,
                                                 float* __restrict__ out) {
  __shared__ float rows[256];
  int t = threadIdx.x;
  int p = blockIdx.x * 4 + (t >> 6), c = t & 63;
  float v = 0.f;
  if (p < n) {
    h2_t h = u2h(fh[(size_t)p * 32 + (c >> 1)]);
    v = fmaxf(fmaf((float)h[c & 1], scsh[c], scsh[64 + c]), 0.f);
  }
  rows[t] = v;
  __syncthreads();
  if (p >= n) return;
  const float* fr = rows + (t >> 6) * 64;
  float a = 0.f;
#pragma unroll 16
  for (int ci = 0; ci < 64; ci++) a = fmaf(fr[ci], we[ci * 64 + c], a);
  out[(size_t)p * 64 + c] = a;
}

// ---------------- dense scatter with fused BN+ReLU ----------------
__global__ void scatter_k(const float* __restrict__ pre, const float* __restrict__ scsh,
                          const int* __restrict__ c3, int n3, float* __restrict__ out0) {
  int t = blockIdx.x * 256 + threadIdx.x;
  if (t >= n3 * 64) return;
  int p = t >> 6, c = t & 63;
  const int* cc = c3 + (size_t)p * 4;
  size_t o = ((((size_t)cc[0] * 64 + c) * 6 + cc[1]) * 100 + cc[2]) * 100 + cc[3];
  out0[o] = fmaxf(fmaf(pre[t], scsh[c], scsh[64 + c]), 0.f);
}

// ---------------- head ----------------
__global__ __launch_bounds__(256) void head_k(const float* __restrict__ X,
                                              const float* __restrict__ fcw,
                                              const float* __restrict__ clsw,
                                              const float* __restrict__ regw,
                                              int n0, float* __restrict__ outc,
                                              float* __restrict__ outr) {
  __shared__ float fl[64 * 161];
  int t = threadIdx.x;
  for (int i = t; i < 64 * 160; i += 256) {
    int r = i / 160, c = i % 160;
    fl[r * 161 + c] = fcw[i];
  }
  __syncthreads();
  int wave = t >> 6, lane = t & 63;
  int u = blockIdx.x * 4 + wave;
  if (u >= n0) return;
  const float* xr = X + (size_t)u * 160;
  const float* wr = fl + (size_t)lane * 161;
  float a = 0.f;
#pragma unroll 8
  for (int i = 0; i < 160; i++) a = fmaf(xr[i], wr[i], a);
  float c = a * clsw[lane];
  float r0 = a * regw[lane], r1 = a * regw[64 + lane], r2 = a * regw[128 + lane];
  for (int off = 32; off; off >>= 1) {
    c  += __shfl_down(c, off);
    r0 += __shfl_down(r0, off);
    r1 += __shfl_down(r1, off);
    r2 += __shfl_down(r2, off);
  }
  if (lane == 0) {
    outc[u] = c;
    outr[(size_t)u * 3] = r0; outr[(size_t)u * 3 + 1] = r1; outr[(size_t)u * 3 + 2] = r2;
  }
}

// ---------------- host ----------------
extern "C" void kernel_launch(void* const* d_in, const int* in_sizes, int n_in,
                              void* d_out, int out_size, void* d_ws, size_t ws_size,
                              hipStream_t stream) {
  const float* vf  = (const float*)d_in[0];
  const int* c0 = (const int*)d_in[1];
  const int* c1 = (const int*)d_in[2];
  const int* c2 = (const int*)d_in[3];
  const int* c3 = (const int*)d_in[4];
  const float* w00 = (const float*)d_in[5];  const float* b00 = (const float*)d_in[6];
  const float* w01 = (const float*)d_in[7];  const float* b01 = (const float*)d_in[8];
  const float* wd0 = (const float*)d_in[9];  const float* bd0 = (const float*)d_in[10];
  const float* w10 = (const float*)d_in[11]; const float* b10 = (const float*)d_in[12];
  const float* w11 = (const float*)d_in[13]; const float* b11 = (const float*)d_in[14];
  const float* wd1 = (const float*)d_in[15]; const float* bd1 = (const float*)d_in[16];
  const float* w20 = (const float*)d_in[17]; const float* b20 = (const float*)d_in[18];
  const float* w21 = (const float*)d_in[19]; const float* b21 = (const float*)d_in[20];
  const float* w22 = (const float*)d_in[21]; const float* b22 = (const float*)d_in[22];
  const float* wd2 = (const float*)d_in[23]; const float* bd2 = (const float*)d_in[24];
  const float* w30 = (const float*)d_in[25]; const float* b30 = (const float*)d_in[26];
  const float* w31 = (const float*)d_in[27]; const float* b31 = (const float*)d_in[28];
  const float* w32 = (const float*)d_in[29]; const float* b32 = (const float*)d_in[30];
  const float* we  = (const float*)d_in[31]; const float* be  = (const float*)d_in[32];
  const float* fcw = (const float*)d_in[33];
  const float* clsw = (const float*)d_in[34];
  const float* regw = (const float*)d_in[35];

  int N0 = in_sizes[1] / 4, N1 = in_sizes[2] / 4, N2 = in_sizes[3] / 4, N3 = in_sizes[4] / 4;
  int maxN = N0; if (N1 > maxN) maxN = N1; if (N2 > maxN) maxN = N2; if (N3 > maxN) maxN = N3;

  auto cdiv = [](int a, int b) { return (a + b - 1) / b; };
  char* p = (char*)d_ws;
  auto alloc = [&](size_t bytes) { char* r = p; p += (bytes + 255) & ~(size_t)255; return r; };

  int* keys0 = (int*)alloc((size_t)N0 * 4);
  int* keys1 = (int*)alloc((size_t)N1 * 4);
  int* keys2 = (int*)alloc((size_t)N2 * 4);
  int* keys3 = (int*)alloc((size_t)N3 * 4);
  int* nbr0  = (int*)alloc((size_t)N0 * 27 * 4);
  int* nbrs1 = (int*)alloc((size_t)N1 * 27 * 4);
  int* nbr1  = (int*)alloc((size_t)N1 * 27 * 4);
  int* nbrs2 = (int*)alloc((size_t)N2 * 27 * 4);
  int* nbr2  = (int*)alloc((size_t)N2 * 27 * 4);
  int* nbrs3 = (int*)alloc((size_t)N3 * 27 * 4);
  int* nbr3  = (int*)alloc((size_t)N3 * 27 * 4);
  float* FA = (float*)alloc((size_t)maxN * 64 * 4);
  float* FB = (float*)alloc((size_t)maxN * 64 * 4);
  float* FC = (float*)alloc((size_t)maxN * 64 * 4);
  unsigned* FAh = (unsigned*)alloc((size_t)maxN * 32 * 4);
  unsigned* FBh = (unsigned*)alloc((size_t)maxN * 32 * 4);
  float* stats = (float*)alloc((size_t)NCH * 64 * 2 * 4);
  float* SC = (float*)alloc((size_t)15 * 128 * 4);
  int* ctrs = (int*)alloc(16 * 4);
  float* wv = (float*)alloc((size_t)N0 * 3 * 4);
  int*   iv = (int*)alloc((size_t)N0 * 3 * 4);
  float* X  = (float*)alloc((size_t)N0 * 160 * 4);
  float* pmb = (float*)alloc((size_t)N0 * 4 * 4);
  float4* kp1 = (float4*)alloc((size_t)N1 * 16);
  float4* kp2 = (float4*)alloc((size_t)N2 * 16);
  float4* kp3 = (float4*)alloc((size_t)N3 * 16);
  int* bsA = (int*)alloc(32);
  unsigned* whbuf = (unsigned*)alloc((size_t)452736 * 4);

  float* out0 = (float*)d_out;
  float* out1 = out0 + 7680000;
  float* outc = out1 + (size_t)N0 * 4;
  float* outr = outc + N0;
  float* partial = out0;  // conv partial scratch until final memset

  auto scsh = [&](int L) { return SC + (size_t)L * 128; };

  const float* wsrc[13] = {w01, wd0, w10, w11, wd1, w20, w21, w22, wd2, w30, w31, w32, nullptr};
  int wcin[13]  = {16, 16, 32, 32, 32, 64, 64, 64, 64, 64, 64, 64, 0};
  int wcout[13] = {16, 32, 32, 32, 64, 64, 64, 64, 64, 64, 64, 64, 0};
  unsigned* wdst[13];
  size_t woff = 0;
  WP13 wp{};
  int nw = 12;
  for (int i = 0; i < nw; i++) {
    wdst[i] = whbuf + woff;
    wp.l[i] = WPrep{wsrc[i], wdst[i], wcin[i], wcout[i]};
    woff += (size_t)27 * (wcin[i] / 2) * wcout[i];
  }
  for (int i = nw; i < 13; i++) wp.l[i] = WPrep{w01, wdst[0], 16, 16};

  hipMemsetAsync(ctrs, 0, 16 * 4, stream);
  wprep_k<<<dim3(216, nw), 256, 0, stream>>>(wp);
  keys_k<<<cdiv(N0, 256), 256, 0, stream>>>(c0, N0, 41, 800, 800, keys0);
  keys_k<<<cdiv(N1, 256), 256, 0, stream>>>(c1, N1, 21, 400, 400, keys1);
  keys_k<<<cdiv(N2, 256), 256, 0, stream>>>(c2, N2, 11, 200, 200, keys2);
  keys_k<<<cdiv(N3, 256), 256, 0, stream>>>(c3, N3, 6, 100, 100, keys3);
  nbr_k<<<cdiv(N0 * 27, 256), 256, 0, stream>>>(c0, N0, keys0, N0, 41, 800, 800, 1, nbr0);
  nbr_k<<<cdiv(N1 * 27, 256), 256, 0, stream>>>(c1, N1, keys0, N0, 41, 800, 800, 2, nbrs1);
  nbr_k<<<cdiv(N1 * 27, 256), 256, 0, stream>>>(c1, N1, keys1, N1, 21, 400, 400, 1, nbr1);
  nbr_k<<<cdiv(N2 * 27, 256), 256, 0, stream>>>(c2, N2, keys1, N1, 21, 400, 400, 2, nbrs2);
  nbr_k<<<cdiv(N2 * 27, 256), 256, 0, stream>>>(c2, N2, keys2, N2, 11, 200, 200, 1, nbr2);
  nbr_k<<<cdiv(N3 * 27, 256), 256, 0, stream>>>(c3, N3, keys2, N2, 11, 200, 200, 2, nbrs3);
  nbr_k<<<cdiv(N3 * 27, 256), 256, 0, stream>>>(c3, N3, keys3, N3, 6, 100, 100, 1, nbr3);
  pm_k<<<cdiv(N0, 256), 256, 0, stream>>>(vf, c0, N0, pmb, out1);
  knnprep_k<<<cdiv(N1, 256), 256, 0, stream>>>(c1, N1, 0.2f, 0.2f, 0.4f, kp1, bsA + 0);
  knnprep_k<<<cdiv(N2, 256), 256, 0, stream>>>(c2, N2, 0.4f, 0.4f, 0.8f, kp2, bsA + 1);
  knnprep_k<<<cdiv(N3, 256), 256, 0, stream>>>(c3, N3, 0.8f, 0.8f, 1.6f, kp3, bsA + 2);

  auto convh = [&](const unsigned* fhin, const int* nb, int wi, int n, int cin, int cout,
                   const float* ss) {
    dim3 g(cdiv(n, 32), NG);
    int gs = n * cout;
    const unsigned* wh = wdst[wi];
    if (cin == 16 && cout == 16)
      convh_k<16, 16><<<g, 128, 0, stream>>>(fhin, nb, wh, n, partial, gs, ss);
    else if (cin == 16 && cout == 32)
      convh_k<16, 32><<<g, 128, 0, stream>>>(fhin, nb, wh, n, partial, gs, ss);
    else if (cin == 32 && cout == 32)
      convh_k<32, 32><<<g, 128, 0, stream>>>(fhin, nb, wh, n, partial, gs, ss);
    else if (cin == 32 && cout == 64)
      convh_k<32, 64><<<g, 128, 0, stream>>>(fhin, nb, wh, n, partial, gs, ss);
    else
      convh_k<64, 64><<<g, 128, 0, stream>>>(fhin, nb, wh, n, partial, gs, ss);
  };
  auto bnp = [&](const float* bnpar, int n, int C, float* pre, unsigned* preh, int L) {
    bn_k<<<NCH, 256, 0, stream>>>(partial, NG, n * C, n, C, pre, preh, stats, bnpar,
                                  scsh(L), ctrs + L);
  };
  auto knn = [&](const float4* kp4, const int* bsl, int nl, const unsigned* fh, int C, int L,
                 int xoff) {
    knn_k<<<cdiv(N0, 4), 256, 0, stream>>>((const float4*)pmb, N0, kp4, nl, bsl, wv, iv);
    interp_k<<<cdiv(N0 * C, 256), 256, 0, stream>>>(fh, C, scsh(L), wv, iv, N0, X, xoff);
  };

  // layer 0: fp32 conv from raw voxel features
  convg_k<4, 16><<<dim3(cdiv(N0, 32), NG), 128, 0, stream>>>(vf, nbr0, w00, N0, partial, N0 * 16);
  bnp(b00, N0, 16, nullptr, FAh, 0);
  convh(FAh, nbr0, 0, N0, 16, 16, scsh(0));   bnp(b01, N0, 16, nullptr, FBh, 1);
  convh(FBh, nbrs1, 1, N1, 16, 32, scsh(1));  bnp(bd0, N1, 32, nullptr, FAh, 2);
  convh(FAh, nbr1, 2, N1, 32, 32, scsh(2));   bnp(b10, N1, 32, nullptr, FBh, 3);
  convh(FBh, nbr1, 3, N1, 32, 32, scsh(3));   bnp(b11, N1, 32, nullptr, FAh, 4);
  knn(kp1, bsA + 0, N1, FAh, 32, 4, 0);
  convh(FAh, nbrs2, 4, N2, 32, 64, scsh(4));  bnp(bd1, N2, 64, nullptr, FBh, 5);
  convh(FBh, nbr2, 5, N2, 64, 64, scsh(5));   bnp(b20, N2, 64, nullptr, FAh, 6);
  convh(FAh, nbr2, 6, N2, 64, 64, scsh(6));   bnp(b21, N2, 64, nullptr, FBh, 7);
  convh(FBh, nbr2, 7, N2, 64, 64, scsh(7));   bnp(b22, N2, 64, nullptr, FAh, 8);
  knn(kp2, bsA + 1, N2, FAh, 64, 8, 32);
  convh(FAh, nbrs3, 8, N3, 64, 64, scsh(8));  bnp(bd2, N3, 64, nullptr, FBh, 9);
  convh(FBh, nbr3, 9, N3, 64, 64, scsh(9));   bnp(b30, N3, 64, nullptr, FAh, 10);
  convh(FAh, nbr3, 10, N3, 64, 64, scsh(10)); bnp(b31, N3, 64, nullptr, FBh, 11);
  convh(FBh, nbr3, 11, N3, 64, 64, scsh(11)); bnp(b32, N3, 64, nullptr, FAh, 12);
  knn(kp3, bsA + 2, N3, FAh, 64, 12, 96);

  conv1x1_k<<<cdiv(N3, 4), 256, 0, stream>>>(FAh, scsh(12), we, N3, FC);
  bn_k<<<NCH, 256, 0, stream>>>(FC, 1, 0, N3, 64, FB, FBh, stats, be, scsh(13), ctrs + 13);
  hipMemsetAsync(d_out, 0, (size_t)7680000 * 4, stream);
  scatter_k<<<cdiv(N3 * 64, 256), 256, 0, stream>>>(FB, scsh(13), c3, N3, out0);
  head_k<<<cdiv(N0, 4), 256, 0, stream>>>(X, fcw, clsw, regw, N0, outc, outr);
}

// Round 18
// 865.973 us; speedup vs baseline: 1.1360x; 1.0753x over previous
//
#include <hip/hip_runtime.h>

#define OFFX 0.0f
#define OFFY -40.0f
#define OFFZ -3.0f
#define BNEPS 1e-3f
#define NCH 128   // bn partial chunks
#define NG 9      // conv tap groups (3 taps each)

typedef _Float16 h2_t __attribute__((ext_vector_type(2)));
__device__ inline h2_t u2h(unsigned u) { union { unsigned u; h2_t h; } x; x.u = u; return x.h; }
__device__ inline unsigned h2u(h2_t h) { union { unsigned u; h2_t h; } x; x.h = h; return x.u; }

// ---------------- keys ----------------
__global__ void keys_k(const int* __restrict__ coords, int n, int D, int H, int W,
                       int* __restrict__ keys) {
  int i = blockIdx.x * 256 + threadIdx.x;
  if (i < n) {
    const int* c = coords + (size_t)i * 4;
    keys[i] = ((c[0] * D + c[1]) * H + c[2]) * W + c[3];
  }
}

// ---------------- neighbor tables ----------------
__global__ void nbr_k(const int* __restrict__ coords, int np, const int* __restrict__ keys, int nk,
                      int D, int H, int W, int scale, int* __restrict__ nbr) {
  int t = blockIdx.x * 256 + threadIdx.x;
  if (t >= np * 27) return;
  int p = t / 27, k = t % 27;
  int kz = k / 9 - 1, ky = (k / 3) % 3 - 1, kx = k % 3 - 1;
  const int* c = coords + (size_t)p * 4;
  int z = c[1] * scale + kz, y = c[2] * scale + ky, x = c[3] * scale + kx;
  int r = -1;
  if (z >= 0 && z < D && y >= 0 && y < H && x >= 0 && x < W) {
    int q = ((c[0] * D + z) * H + y) * W + x;
    int lo = 0, hi = nk;
    while (lo < hi) { int m = (lo + hi) >> 1; if (keys[m] < q) lo = m + 1; else hi = m; }
    if (lo < nk && keys[lo] == q) r = lo;
  }
  nbr[t] = r;
}

// ---------------- weight prep: fp32 [27][CIN][COUT] -> h2 [27][CIN/2][COUT] ----------------
struct WPrep { const float* src; unsigned* dst; int cin; int cout; };
struct WP13 { WPrep l[13]; };
__global__ void wprep_k(WP13 a) {
  WPrep w = a.l[blockIdx.y];
  int cp2 = w.cin / 2;
  int tot = 27 * cp2 * w.cout;
  int i = blockIdx.x * 256 + threadIdx.x;
  if (i >= tot) return;
  int o = i % w.cout, rest = i / w.cout;
  int cp = rest % cp2, k = rest / cp2;
  float lo = w.src[((size_t)k * w.cin + 2 * cp) * w.cout + o];
  float hi = w.src[((size_t)k * w.cin + 2 * cp + 1) * w.cout + o];
  h2_t h; h[0] = (_Float16)lo; h[1] = (_Float16)hi;
  w.dst[i] = h2u(h);
}

// ---------------- layer-0 conv (fp32, CIN=4): LDS tile-GEMM TP=32 ----------------
template<int CIN, int COUT>
__global__ __launch_bounds__(128) void convg_k(const float* __restrict__ feats,
                                               const int* __restrict__ nbr,
                                               const float* __restrict__ w, int n,
                                               float* __restrict__ partial, int gstride) {
  constexpr int TP = 32;
  constexpr int LDP = 36;
  constexpr int CO = COUT / 16;
  __shared__ float G[CIN * LDP];
  int tid = threadIdx.x;
  int pg = tid >> 4, cg = tid & 15;
  int p0 = blockIdx.x * TP;
  int k0 = blockIdx.y * 3;
  float acc[4][CO];
#pragma unroll
  for (int i = 0; i < 4; i++)
#pragma unroll
    for (int j = 0; j < CO; j++) acc[i][j] = 0.f;

  for (int kk = 0; kk < 3; kk++) {
    int k = k0 + kk;
    __syncthreads();
    for (int ch = tid; ch < TP * CIN / 4; ch += 128) {
      int r = ch & (TP - 1), c4 = ch / TP;
      int p = p0 + r;
      int idx = (p < n) ? nbr[(size_t)p * 27 + k] : -1;
      float4 fv = make_float4(0.f, 0.f, 0.f, 0.f);
      if (idx >= 0) fv = *(const float4*)(feats + (size_t)idx * CIN + c4 * 4);
      G[(c4 * 4 + 0) * LDP + r] = fv.x;
      G[(c4 * 4 + 1) * LDP + r] = fv.y;
      G[(c4 * 4 + 2) * LDP + r] = fv.z;
      G[(c4 * 4 + 3) * LDP + r] = fv.w;
    }
    __syncthreads();
    const float* wk = w + (size_t)k * CIN * COUT + cg * CO;
#pragma unroll
    for (int c = 0; c < CIN; c++) {
      float4 g4 = *(const float4*)&G[c * LDP + pg * 4];
      float wv[CO];
      if constexpr (CO == 4)      *(float4*)wv = *(const float4*)(wk + c * COUT);
      else if constexpr (CO == 2) *(float2*)wv = *(const float2*)(wk + c * COUT);
      else                        wv[0] = wk[c * COUT];
      float gp[4] = {g4.x, g4.y, g4.z, g4.w};
#pragma unroll
      for (int i = 0; i < 4; i++)
#pragma unroll
        for (int j = 0; j < CO; j++) acc[i][j] = fmaf(gp[i], wv[j], acc[i][j]);
    }
  }
#pragma unroll
  for (int i = 0; i < 4; i++) {
    int p = p0 + pg * 4 + i;
    if (p < n) {
      float* dst = partial + (size_t)blockIdx.y * gstride + (size_t)p * COUT + cg * CO;
      if constexpr (CO == 4)      *(float4*)dst = *(float4*)acc[i];
      else if constexpr (CO == 2) *(float2*)dst = *(float2*)acc[i];
      else                        dst[0] = acc[i][0];
    }
  }
}

// ---------------- f16 conv: software-pipelined gather, fdot2, fused BN+ReLU.
// Partials stored h2-packed when CO>=2 (halves partial traffic); fp32 when CO==1. ----------------
template<int CIN, int COUT>
__global__ __launch_bounds__(128) void convh_k(const unsigned* __restrict__ fh,
                                               const int* __restrict__ nbr,
                                               const unsigned* __restrict__ wh, int n,
                                               void* __restrict__ partial, int gstride,
                                               const float* __restrict__ scsh) {
  constexpr int TP = 32;
  constexpr int LDPH = 36;
  constexpr int CO = COUT / 16;
  constexpr int CP = CIN / 2;
  constexpr bool H2P = (CO >= 2);
  __shared__ unsigned H[CP * LDPH];
  int tid = threadIdx.x;
  int pg = tid >> 4, cg = tid & 15;
  int p0 = blockIdx.x * TP;
  int k0 = blockIdx.y * 3;
  int r = tid & 31;
  int p = p0 + r;
  int sidx[3];
  if (p < n) {
    const int* nb = nbr + (size_t)p * 27 + k0;
    sidx[0] = nb[0]; sidx[1] = nb[1]; sidx[2] = nb[2];
  } else { sidx[0] = sidx[1] = sidx[2] = -1; }

  float acc[4][CO];
#pragma unroll
  for (int i = 0; i < 4; i++)
#pragma unroll
    for (int j = 0; j < CO; j++) acc[i][j] = 0.f;

  if constexpr (CIN >= 32) {
    constexpr int NLD = CIN / 32;
    uint4 pf[NLD];
    {
      int idx = sidx[0];
#pragma unroll
      for (int it = 0; it < NLD; it++) {
        int q = (tid >> 5) + it * 4;
        pf[it] = (idx >= 0) ? *(const uint4*)(fh + (size_t)idx * CP + q * 4)
                            : make_uint4(0, 0, 0, 0);
      }
    }
    for (int kk = 0; kk < 3; kk++) {
      bool ok = sidx[kk] >= 0;
      __syncthreads();
#pragma unroll
      for (int it = 0; it < NLD; it++) {
        int q = (tid >> 5) + it * 4;
        unsigned uu[4] = {pf[it].x, pf[it].y, pf[it].z, pf[it].w};
#pragma unroll
        for (int j = 0; j < 4; j++) {
          int cp = q * 4 + j;
          unsigned outw = 0;
          if (ok) {
            h2_t h = u2h(uu[j]);
            float lo = fmaxf(fmaf((float)h[0], scsh[2 * cp], scsh[CIN + 2 * cp]), 0.f);
            float hi = fmaxf(fmaf((float)h[1], scsh[2 * cp + 1], scsh[CIN + 2 * cp + 1]), 0.f);
            h2_t o; o[0] = (_Float16)lo; o[1] = (_Float16)hi;
            outw = h2u(o);
          }
          H[cp * LDPH + r] = outw;
        }
      }
      if (kk < 2) {
        int idx = sidx[kk + 1];
#pragma unroll
        for (int it = 0; it < NLD; it++) {
          int q = (tid >> 5) + it * 4;
          pf[it] = (idx >= 0) ? *(const uint4*)(fh + (size_t)idx * CP + q * 4)
                              : make_uint4(0, 0, 0, 0);
        }
      }
      __syncthreads();
      const unsigned* wk = wh + (size_t)(k0 + kk) * CP * COUT + cg * CO;
#pragma unroll 8
      for (int cp = 0; cp < CP; cp++) {
        uint4 g4 = *(const uint4*)&H[cp * LDPH + pg * 4];
        unsigned gg[4] = {g4.x, g4.y, g4.z, g4.w};
        unsigned wv[CO];
        if constexpr (CO == 4)      *(uint4*)wv = *(const uint4*)(wk + cp * COUT);
        else if constexpr (CO == 2) *(uint2*)wv = *(const uint2*)(wk + cp * COUT);
        else                        wv[0] = wk[cp * COUT];
#pragma unroll
        for (int i = 0; i < 4; i++)
#pragma unroll
          for (int j = 0; j < CO; j++)
            acc[i][j] = __builtin_amdgcn_fdot2(u2h(gg[i]), u2h(wv[j]), acc[i][j], false);
      }
    }
  } else {  // CIN == 16
    int q = tid >> 5;
    uint2 pf2;
    {
      int idx = sidx[0];
      pf2 = (idx >= 0) ? *(const uint2*)(fh + (size_t)idx * CP + q * 2) : make_uint2(0, 0);
    }
    for (int kk = 0; kk < 3; kk++) {
      bool ok = sidx[kk] >= 0;
      __syncthreads();
      unsigned uu[2] = {pf2.x, pf2.y};
#pragma unroll
      for (int j = 0; j < 2; j++) {
        int cp = q * 2 + j;
        unsigned outw = 0;
        if (ok) {
          h2_t h = u2h(uu[j]);
          float lo = fmaxf(fmaf((float)h[0], scsh[2 * cp], scsh[CIN + 2 * cp]), 0.f);
          float hi = fmaxf(fmaf((float)h[1], scsh[2 * cp + 1], scsh[CIN + 2 * cp + 1]), 0.f);
          h2_t o; o[0] = (_Float16)lo; o[1] = (_Float16)hi;
          outw = h2u(o);
        }
        H[cp * LDPH + r] = outw;
      }
      if (kk < 2) {
        int idx = sidx[kk + 1];
        pf2 = (idx >= 0) ? *(const uint2*)(fh + (size_t)idx * CP + q * 2) : make_uint2(0, 0);
      }
      __syncthreads();
      const unsigned* wk = wh + (size_t)(k0 + kk) * CP * COUT + cg * CO;
#pragma unroll
      for (int cp = 0; cp < CP; cp++) {
        uint4 g4 = *(const uint4*)&H[cp * LDPH + pg * 4];
        unsigned gg[4] = {g4.x, g4.y, g4.z, g4.w};
        unsigned wv[CO];
        if constexpr (CO == 4)      *(uint4*)wv = *(const uint4*)(wk + cp * COUT);
        else if constexpr (CO == 2) *(uint2*)wv = *(const uint2*)(wk + cp * COUT);
        else                        wv[0] = wk[cp * COUT];
#pragma unroll
        for (int i = 0; i < 4; i++)
#pragma unroll
          for (int j = 0; j < CO; j++)
            acc[i][j] = __builtin_amdgcn_fdot2(u2h(gg[i]), u2h(wv[j]), acc[i][j], false);
      }
    }
  }
#pragma unroll
  for (int i = 0; i < 4; i++) {
    int pp = p0 + pg * 4 + i;
    if (pp < n) {
      if constexpr (H2P) {
        unsigned* dst = (unsigned*)partial + (size_t)blockIdx.y * gstride
                      + (size_t)pp * (COUT / 2) + cg * (CO / 2);
        if constexpr (CO == 4) {
          h2_t a; a[0] = (_Float16)acc[i][0]; a[1] = (_Float16)acc[i][1];
          h2_t b; b[0] = (_Float16)acc[i][2]; b[1] = (_Float16)acc[i][3];
          *(uint2*)dst = make_uint2(h2u(a), h2u(b));
        } else {
          h2_t a; a[0] = (_Float16)acc[i][0]; a[1] = (_Float16)acc[i][1];
          dst[0] = h2u(a);
        }
      } else {
        float* dst = (float*)partial + (size_t)blockIdx.y * gstride
                   + (size_t)pp * COUT + cg * CO;
        dst[0] = acc[i][0];
      }
    }
  }
}

// ---------------- bn: sum partials (h2 or fp32) -> preh (h2) + opt fp32 pre + stats;
// last block finalizes (sc, sh) with parallel chunk reduction ----------------
template<bool H2P>
__global__ void bn_k(const void* __restrict__ partial, int G, int gstride, int n, int C,
                     float* __restrict__ pre, unsigned* __restrict__ preh,
                     float* __restrict__ stats, const float* __restrict__ bnp,
                     float* __restrict__ scsh, int* __restrict__ ctr) {
  __shared__ float l1e[256], l2e[256], l1o[256], l2o[256];
  __shared__ int lastf;
  int t = threadIdx.x;
  int total = n * C;
  float s1e = 0.f, s2e = 0.f, s1o = 0.f, s2o = 0.f;
  for (int i2 = (blockIdx.x * 256 + t) * 2; i2 < total; i2 += NCH * 512) {
    float v0 = 0.f, v1 = 0.f;
    if constexpr (H2P) {
      const unsigned* ph = (const unsigned*)partial;
      for (int g = 0; g < G; g++) {
        h2_t h = u2h(ph[(size_t)g * gstride + (i2 >> 1)]);
        v0 += (float)h[0]; v1 += (float)h[1];
      }
    } else {
      const float* pf = (const float*)partial;
      for (int g = 0; g < G; g++) {
        float2 pv = *(const float2*)(pf + (size_t)g * gstride + i2);
        v0 += pv.x; v1 += pv.y;
      }
    }
    if (pre) *(float2*)(pre + i2) = make_float2(v0, v1);
    h2_t h; h[0] = (_Float16)v0; h[1] = (_Float16)v1;
    preh[i2 >> 1] = h2u(h);
    s1e += v0; s2e += v0 * v0; s1o += v1; s2o += v1 * v1;
  }
  l1e[t] = s1e; l2e[t] = s2e; l1o[t] = s1o; l2o[t] = s2o;
  for (int s = 128; s >= C / 2; s >>= 1) {
    __syncthreads();
    if (t < s) {
      l1e[t] += l1e[t + s]; l2e[t] += l2e[t + s];
      l1o[t] += l1o[t + s]; l2o[t] += l2o[t + s];
    }
  }
  __syncthreads();
  if (t < C / 2) {
    stats[((size_t)blockIdx.x * C + 2 * t) * 2]     = l1e[t];
    stats[((size_t)blockIdx.x * C + 2 * t) * 2 + 1] = l2e[t];
    stats[((size_t)blockIdx.x * C + 2 * t + 1) * 2]     = l1o[t];
    stats[((size_t)blockIdx.x * C + 2 * t + 1) * 2 + 1] = l2o[t];
  }
  __threadfence();
  __syncthreads();
  if (t == 0) lastf = (atomicAdd(ctr, 1) == NCH - 1) ? 1 : 0;
  __syncthreads();
  if (lastf) {
    __threadfence();
    // parallel finalize: 256/C threads per channel
    int c = t % C, sub = t / C;
    int TPC = 256 / C;
    float a1 = 0.f, a2 = 0.f;
    for (int ch = sub; ch < NCH; ch += TPC) {
      a1 += stats[((size_t)ch * C + c) * 2];
      a2 += stats[((size_t)ch * C + c) * 2 + 1];
    }
    l1e[t] = a1; l2e[t] = a2;
    for (int s = 128; s >= C; s >>= 1) {
      __syncthreads();
      if (t < s) { l1e[t] += l1e[t + s]; l2e[t] += l2e[t + s]; }
    }
    __syncthreads();
    if (t < C) {
      float m = l1e[t] / n;
      float v = l2e[t] / n - m * m;
      float sc = bnp[t] / sqrtf(v + BNEPS);
      scsh[t] = sc;
      scsh[C + t] = bnp[C + t] - m * sc;
    }
  }
}

// ---------------- points_mean ----------------
__global__ void pm_k(const float* __restrict__ vf, const int* __restrict__ c0, int n0,
                     float* __restrict__ pm, float* __restrict__ out1) {
  int i = blockIdx.x * 256 + threadIdx.x;
  if (i >= n0) return;
  float b = (float)c0[(size_t)i * 4];
  float x = vf[(size_t)i * 4], y = vf[(size_t)i * 4 + 1], z = vf[(size_t)i * 4 + 2];
  pm[(size_t)i * 4] = b; pm[(size_t)i * 4 + 1] = x; pm[(size_t)i * 4 + 2] = y; pm[(size_t)i * 4 + 3] = z;
  out1[(size_t)i * 4] = b; out1[(size_t)i * 4 + 1] = x; out1[(size_t)i * 4 + 2] = y; out1[(size_t)i * 4 + 3] = z;
}

// ---------------- knn prep ----------------
__global__ void knnprep_k(const int* __restrict__ coords, int nl, float vx, float vy, float vz,
                          float4* __restrict__ kp4, int* __restrict__ bs) {
  int i = blockIdx.x * 256 + threadIdx.x;
  if (i >= nl) return;
  const int* c = coords + (size_t)i * 4;
  kp4[i] = make_float4(OFFX + (c[3] + 0.5f) * vx,
                       OFFY + (c[2] + 0.5f) * vy,
                       OFFZ + (c[1] + 0.5f) * vz, (float)c[0]);
  if (c[0] == 0 && (i + 1 == nl || coords[(size_t)(i + 1) * 4] == 1)) bs[0] = i + 1;
}

// ---------------- 3-NN: 4 waves/block share LDS-staged chunks; wave per unknown ----------------
__global__ __launch_bounds__(256) void knn_k(const float4* __restrict__ pm4, int n0,
                                             const float4* __restrict__ kp4, int nl,
                                             const int* __restrict__ bsp,
                                             float* __restrict__ wv, int* __restrict__ iv) {
  __shared__ __align__(16) float4 kp[256];
  __shared__ int bl[4], bh[4];
  int tid = threadIdx.x;
  int wave = tid >> 6, lane = tid & 63;
  int u = blockIdx.x * 4 + wave;
  bool valid = u < n0;
  float4 up = pm4[valid ? u : (n0 - 1)];
  int bs = bsp[0];
  int lo = (up.x == 0.f) ? 0 : bs;
  int hi = (up.x == 0.f) ? bs : nl;
  if (!valid) { lo = 0; hi = 0; }
  if (lane == 0) { bl[wave] = valid ? lo : 0x7fffffff; bh[wave] = valid ? hi : 0; }
  __syncthreads();
  int blo = min(min(bl[0], bl[1]), min(bl[2], bl[3]));
  int bhi = max(max(bh[0], bh[1]), max(bh[2], bh[3]));
  float ux = up.y, uy = up.z, uz = up.w;
  float d0 = 3e38f, d1 = 3e38f, d2 = 3e38f;
  int i0 = -1, i1 = -1, i2 = -1;
#define INS1(DD, GI) { \
    bool l0 = (DD) < d0, l1 = (DD) < d1, l2 = (DD) < d2; \
    i2 = l2 ? (l1 ? i1 : (GI)) : i2; \
    i1 = l1 ? (l0 ? i0 : (GI)) : i1; \
    i0 = l0 ? (GI) : i0; \
    float t1_ = __builtin_amdgcn_fmed3f(d0, d1, (DD)); \
    float t2_ = __builtin_amdgcn_fmed3f(d1, d2, (DD)); \
    d0 = fminf(d0, (DD)); d1 = t1_; d2 = t2_; }
#define DIST(Q) fmaf(ux - (Q).x, ux - (Q).x, fmaf(uy - (Q).y, uy - (Q).y, (uz - (Q).z) * (uz - (Q).z)))
  for (int cb = blo; cb < bhi; cb += 256) {
    int m = bhi - cb; if (m > 256) m = 256;
    __syncthreads();
    if (tid < m) kp[tid] = kp4[cb + tid];
    __syncthreads();
    if (cb + 256 <= lo || cb >= hi) continue;
    if (m == 256 && cb >= lo && cb + 256 <= hi) {
      float4 q0 = kp[lane], q1 = kp[lane + 64], q2 = kp[lane + 128], q3 = kp[lane + 192];
      float a0 = DIST(q0), a1 = DIST(q1), a2 = DIST(q2), a3 = DIST(q3);
      if (__any((a0 < d2) | (a1 < d2) | (a2 < d2) | (a3 < d2))) {
        INS1(a0, cb + lane) INS1(a1, cb + lane + 64)
        INS1(a2, cb + lane + 128) INS1(a3, cb + lane + 192)
      }
    } else {
#pragma unroll
      for (int j = 0; j < 4; j++) {
        int i = lane + 64 * j;
        int e = cb + i;
        if (i < m && e >= lo && e < hi) {
          float4 q = kp[i];
          float dd = DIST(q);
          INS1(dd, e)
        }
      }
    }
  }
#pragma unroll
  for (int off = 1; off < 64; off <<= 1) {
    float e0 = __shfl_xor(d0, off), e1 = __shfl_xor(d1, off), e2 = __shfl_xor(d2, off);
    int j0 = __shfl_xor(i0, off), j1 = __shfl_xor(i1, off), j2 = __shfl_xor(i2, off);
    INS1(e0, j0) INS1(e1, j1) INS1(e2, j2)
  }
#undef DIST
#undef INS1
  if (valid && lane == 0) {
    float w0 = 1.f / (d0 + 1e-8f), w1 = 1.f / (d1 + 1e-8f), w2 = 1.f / (d2 + 1e-8f);
    float s = w0 + w1 + w2;
    wv[(size_t)u * 3] = w0 / s; wv[(size_t)u * 3 + 1] = w1 / s; wv[(size_t)u * 3 + 2] = w2 / s;
    iv[(size_t)u * 3] = i0; iv[(size_t)u * 3 + 1] = i1; iv[(size_t)u * 3 + 2] = i2;
  }
}

// interp with fused BN+ReLU, reading h2 pre-activations
__global__ void interp_k(const unsigned* __restrict__ fh, int C, const float* __restrict__ scsh,
                         const float* __restrict__ wv, const int* __restrict__ iv, int n0,
                         float* __restrict__ X, int xoff) {
  int t = blockIdx.x * 256 + threadIdx.x;
  if (t >= n0 * C) return;
  int u = t / C, c = t % C;
  int cp = c >> 1, sel = c & 1;
  int CP = C >> 1;
  float sc = scsh[c], sh = scsh[C + c];
  h2_t h0 = u2h(fh[(size_t)iv[(size_t)u * 3]     * CP + cp]);
  h2_t h1 = u2h(fh[(size_t)iv[(size_t)u * 3 + 1] * CP + cp]);
  h2_t h2v = u2h(fh[(size_t)iv[(size_t)u * 3 + 2] * CP + cp]);
  float a0 = fmaxf(fmaf((float)h0[sel], sc, sh), 0.f);
  float a1 = fmaxf(fmaf((float)h1[sel], sc, sh), 0.f);
  float a2 = fmaxf(fmaf((float)h2v[sel], sc, sh), 0.f);
  X[(size_t)u * 160 + xoff + c] = wv[(size_t)u * 3] * a0 + wv[(size_t)u * 3 + 1] * a1
                                + wv[(size_t)u * 3 + 2] * a2;
}

// ---------------- extra 1x1 conv, h2 input with fused BN ----------------
__global__ __launch_bounds__(256) void conv1x1_k(const unsigned* __restrict__ fh,
                                                 const float* __restrict__ scsh,
                                                 const float* __restrict__ we, int n,
                                                 float* __restrict__ out) {
  __shared__ float rows[256];
  int t = threadIdx.x;
  int p = blockIdx.x * 4 + (t >> 6), c = t & 63;
  float v = 0.f;
  if (p < n) {
    h2_t h = u2h(fh[(size_t)p * 32 + (c >> 1)]);
    v = fmaxf(fmaf((float)h[c & 1], scsh[c], scsh[64 + c]), 0.f);
  }
  rows[t] = v;
  __syncthreads();
  if (p >= n) return;
  const float* fr = rows + (t >> 6) * 64;
  float a = 0.f;
#pragma unroll 16
  for (int ci = 0; ci < 64; ci++) a = fmaf(fr[ci], we[ci * 64 + c], a);
  out[(size_t)p * 64 + c] = a;
}

// ---------------- dense scatter with fused BN+ReLU ----------------
__global__ void scatter_k(const float* __restrict__ pre, const float* __restrict__ scsh,
                          const int* __restrict__ c3, int n3, float* __restrict__ out0) {
  int t = blockIdx.x * 256 + threadIdx.x;
  if (t >= n3 * 64) return;
  int p = t >> 6, c = t & 63;
  const int* cc = c3 + (size_t)p * 4;
  size_t o = ((((size_t)cc[0] * 64 + c) * 6 + cc[1]) * 100 + cc[2]) * 100 + cc[3];
  out0[o] = fmaxf(fmaf(pre[t], scsh[c], scsh[64 + c]), 0.f);
}

// ---------------- head ----------------
__global__ __launch_bounds__(256) void head_k(const float* __restrict__ X,
                                              const float* __restrict__ fcw,
                                              const float* __restrict__ clsw,
                                              const float* __restrict__ regw,
                                              int n0, float* __restrict__ outc,
                                              float* __restrict__ outr) {
  __shared__ float fl[64 * 161];
  int t = threadIdx.x;
  for (int i = t; i < 64 * 160; i += 256) {
    int r = i / 160, c = i % 160;
    fl[r * 161 + c] = fcw[i];
  }
  __syncthreads();
  int wave = t >> 6, lane = t & 63;
  int u = blockIdx.x * 4 + wave;
  if (u >= n0) return;
  const float* xr = X + (size_t)u * 160;
  const float* wr = fl + (size_t)lane * 161;
  float a = 0.f;
#pragma unroll 8
  for (int i = 0; i < 160; i++) a = fmaf(xr[i], wr[i], a);
  float c = a * clsw[lane];
  float r0 = a * regw[lane], r1 = a * regw[64 + lane], r2 = a * regw[128 + lane];
  for (int off = 32; off; off >>= 1) {
    c  += __shfl_down(c, off);
    r0 += __shfl_down(r0, off);
    r1 += __shfl_down(r1, off);
    r2 += __shfl_down(r2, off);
  }
  if (lane == 0) {
    outc[u] = c;
    outr[(size_t)u * 3] = r0; outr[(size_t)u * 3 + 1] = r1; outr[(size_t)u * 3 + 2] = r2;
  }
}

// ---------------- host ----------------
extern "C" void kernel_launch(void* const* d_in, const int* in_sizes, int n_in,
                              void* d_out, int out_size, void* d_ws, size_t ws_size,
                              hipStream_t stream) {
  const float* vf  = (const float*)d_in[0];
  const int* c0 = (const int*)d_in[1];
  const int* c1 = (const int*)d_in[2];
  const int* c2 = (const int*)d_in[3];
  const int* c3 = (const int*)d_in[4];
  const float* w00 = (const float*)d_in[5];  const float* b00 = (const float*)d_in[6];
  const float* w01 = (const float*)d_in[7];  const float* b01 = (const float*)d_in[8];
  const float* wd0 = (const float*)d_in[9];  const float* bd0 = (const float*)d_in[10];
  const float* w10 = (const float*)d_in[11]; const float* b10 = (const float*)d_in[12];
  const float* w11 = (const float*)d_in[13]; const float* b11 = (const float*)d_in[14];
  const float* wd1 = (const float*)d_in[15]; const float* bd1 = (const float*)d_in[16];
  const float* w20 = (const float*)d_in[17]; const float* b20 = (const float*)d_in[18];
  const float* w21 = (const float*)d_in[19]; const float* b21 = (const float*)d_in[20];
  const float* w22 = (const float*)d_in[21]; const float* b22 = (const float*)d_in[22];
  const float* wd2 = (const float*)d_in[23]; const float* bd2 = (const float*)d_in[24];
  const float* w30 = (const float*)d_in[25]; const float* b30 = (const float*)d_in[26];
  const float* w31 = (const float*)d_in[27]; const float* b31 = (const float*)d_in[28];
  const float* w32 = (const float*)d_in[29]; const float* b32 = (const float*)d_in[30];
  const float* we  = (const float*)d_in[31]; const float* be  = (const float*)d_in[32];
  const float* fcw = (const float*)d_in[33];
  const float* clsw = (const float*)d_in[34];
  const float* regw = (const float*)d_in[35];

  int N0 = in_sizes[1] / 4, N1 = in_sizes[2] / 4, N2 = in_sizes[3] / 4, N3 = in_sizes[4] / 4;
  int maxN = N0; if (N1 > maxN) maxN = N1; if (N2 > maxN) maxN = N2; if (N3 > maxN) maxN = N3;

  auto cdiv = [](int a, int b) { return (a + b - 1) / b; };
  char* p = (char*)d_ws;
  auto alloc = [&](size_t bytes) { char* r = p; p += (bytes + 255) & ~(size_t)255; return r; };

  int* keys0 = (int*)alloc((size_t)N0 * 4);
  int* keys1 = (int*)alloc((size_t)N1 * 4);
  int* keys2 = (int*)alloc((size_t)N2 * 4);
  int* keys3 = (int*)alloc((size_t)N3 * 4);
  int* nbr0  = (int*)alloc((size_t)N0 * 27 * 4);
  int* nbrs1 = (int*)alloc((size_t)N1 * 27 * 4);
  int* nbr1  = (int*)alloc((size_t)N1 * 27 * 4);
  int* nbrs2 = (int*)alloc((size_t)N2 * 27 * 4);
  int* nbr2  = (int*)alloc((size_t)N2 * 27 * 4);
  int* nbrs3 = (int*)alloc((size_t)N3 * 27 * 4);
  int* nbr3  = (int*)alloc((size_t)N3 * 27 * 4);
  float* FA = (float*)alloc((size_t)maxN * 64 * 4);
  float* FB = (float*)alloc((size_t)maxN * 64 * 4);
  float* FC = (float*)alloc((size_t)maxN * 64 * 4);
  unsigned* FAh = (unsigned*)alloc((size_t)maxN * 32 * 4);
  unsigned* FBh = (unsigned*)alloc((size_t)maxN * 32 * 4);
  float* stats = (float*)alloc((size_t)NCH * 64 * 2 * 4);
  float* SC = (float*)alloc((size_t)15 * 128 * 4);
  int* ctrs = (int*)alloc(16 * 4);
  float* wv = (float*)alloc((size_t)N0 * 3 * 4);
  int*   iv = (int*)alloc((size_t)N0 * 3 * 4);
  float* X  = (float*)alloc((size_t)N0 * 160 * 4);
  float* pmb = (float*)alloc((size_t)N0 * 4 * 4);
  float4* kp1 = (float4*)alloc((size_t)N1 * 16);
  float4* kp2 = (float4*)alloc((size_t)N2 * 16);
  float4* kp3 = (float4*)alloc((size_t)N3 * 16);
  int* bsA = (int*)alloc(32);
  unsigned* whbuf = (unsigned*)alloc((size_t)452736 * 4);

  float* out0 = (float*)d_out;
  float* out1 = out0 + 7680000;
  float* outc = out1 + (size_t)N0 * 4;
  float* outr = outc + N0;
  void* partial = out0;  // conv partial scratch until final memset

  auto scsh = [&](int L) { return SC + (size_t)L * 128; };

  const float* wsrc[13] = {w01, wd0, w10, w11, wd1, w20, w21, w22, wd2, w30, w31, w32, nullptr};
  int wcin[13]  = {16, 16, 32, 32, 32, 64, 64, 64, 64, 64, 64, 64, 0};
  int wcout[13] = {16, 32, 32, 32, 64, 64, 64, 64, 64, 64, 64, 64, 0};
  unsigned* wdst[13];
  size_t woff = 0;
  WP13 wp{};
  int nw = 12;
  for (int i = 0; i < nw; i++) {
    wdst[i] = whbuf + woff;
    wp.l[i] = WPrep{wsrc[i], wdst[i], wcin[i], wcout[i]};
    woff += (size_t)27 * (wcin[i] / 2) * wcout[i];
  }
  for (int i = nw; i < 13; i++) wp.l[i] = WPrep{w01, wdst[0], 16, 16};

  hipMemsetAsync(ctrs, 0, 16 * 4, stream);
  wprep_k<<<dim3(216, nw), 256, 0, stream>>>(wp);
  keys_k<<<cdiv(N0, 256), 256, 0, stream>>>(c0, N0, 41, 800, 800, keys0);
  keys_k<<<cdiv(N1, 256), 256, 0, stream>>>(c1, N1, 21, 400, 400, keys1);
  keys_k<<<cdiv(N2, 256), 256, 0, stream>>>(c2, N2, 11, 200, 200, keys2);
  keys_k<<<cdiv(N3, 256), 256, 0, stream>>>(c3, N3, 6, 100, 100, keys3);
  nbr_k<<<cdiv(N0 * 27, 256), 256, 0, stream>>>(c0, N0, keys0, N0, 41, 800, 800, 1, nbr0);
  nbr_k<<<cdiv(N1 * 27, 256), 256, 0, stream>>>(c1, N1, keys0, N0, 41, 800, 800, 2, nbrs1);
  nbr_k<<<cdiv(N1 * 27, 256), 256, 0, stream>>>(c1, N1, keys1, N1, 21, 400, 400, 1, nbr1);
  nbr_k<<<cdiv(N2 * 27, 256), 256, 0, stream>>>(c2, N2, keys1, N1, 21, 400, 400, 2, nbrs2);
  nbr_k<<<cdiv(N2 * 27, 256), 256, 0, stream>>>(c2, N2, keys2, N2, 11, 200, 200, 1, nbr2);
  nbr_k<<<cdiv(N3 * 27, 256), 256, 0, stream>>>(c3, N3, keys2, N2, 11, 200, 200, 2, nbrs3);
  nbr_k<<<cdiv(N3 * 27, 256), 256, 0, stream>>>(c3, N3, keys3, N3, 6, 100, 100, 1, nbr3);
  pm_k<<<cdiv(N0, 256), 256, 0, stream>>>(vf, c0, N0, pmb, out1);
  knnprep_k<<<cdiv(N1, 256), 256, 0, stream>>>(c1, N1, 0.2f, 0.2f, 0.4f, kp1, bsA + 0);
  knnprep_k<<<cdiv(N2, 256), 256, 0, stream>>>(c2, N2, 0.4f, 0.4f, 0.8f, kp2, bsA + 1);
  knnprep_k<<<cdiv(N3, 256), 256, 0, stream>>>(c3, N3, 0.8f, 0.8f, 1.6f, kp3, bsA + 2);

  auto convh = [&](const unsigned* fhin, const int* nb, int wi, int n, int cin, int cout,
                   const float* ss) {
    dim3 g(cdiv(n, 32), NG);
    int gs = (cout >= 32) ? n * cout / 2 : n * cout;  // uints when h2-packed
    const unsigned* wh = wdst[wi];
    if (cin == 16 && cout == 16)
      convh_k<16, 16><<<g, 128, 0, stream>>>(fhin, nb, wh, n, partial, gs, ss);
    else if (cin == 16 && cout == 32)
      convh_k<16, 32><<<g, 128, 0, stream>>>(fhin, nb, wh, n, partial, gs, ss);
    else if (cin == 32 && cout == 32)
      convh_k<32, 32><<<g, 128, 0, stream>>>(fhin, nb, wh, n, partial, gs, ss);
    else if (cin == 32 && cout == 64)
      convh_k<32, 64><<<g, 128, 0, stream>>>(fhin, nb, wh, n, partial, gs, ss);
    else
      convh_k<64, 64><<<g, 128, 0, stream>>>(fhin, nb, wh, n, partial, gs, ss);
  };
  auto bnp = [&](const float* bnpar, int n, int C, float* pre, unsigned* preh, int L, bool h2p) {
    int gs = h2p ? n * C / 2 : n * C;
    if (h2p)
      bn_k<true><<<NCH, 256, 0, stream>>>(partial, NG, gs, n, C, pre, preh, stats, bnpar,
                                          scsh(L), ctrs + L);
    else
      bn_k<false><<<NCH, 256, 0, stream>>>(partial, NG, gs, n, C, pre, preh, stats, bnpar,
                                           scsh(L), ctrs + L);
  };
  auto knn = [&](const float4* kp4, const int* bsl, int nl, const unsigned* fh, int C, int L,
                 int xoff) {
    knn_k<<<cdiv(N0, 4), 256, 0, stream>>>((const float4*)pmb, N0, kp4, nl, bsl, wv, iv);
    interp_k<<<cdiv(N0 * C, 256), 256, 0, stream>>>(fh, C, scsh(L), wv, iv, N0, X, xoff);
  };

  // layer 0: fp32 conv from raw voxel features
  convg_k<4, 16><<<dim3(cdiv(N0, 32), NG), 128, 0, stream>>>(vf, nbr0, w00, N0,
                                                             (float*)partial, N0 * 16);
  bnp(b00, N0, 16, nullptr, FAh, 0, false);
  convh(FAh, nbr0, 0, N0, 16, 16, scsh(0));   bnp(b01, N0, 16, nullptr, FBh, 1, false);
  convh(FBh, nbrs1, 1, N1, 16, 32, scsh(1));  bnp(bd0, N1, 32, nullptr, FAh, 2, true);
  convh(FAh, nbr1, 2, N1, 32, 32, scsh(2));   bnp(b10, N1, 32, nullptr, FBh, 3, true);
  convh(FBh, nbr1, 3, N1, 32, 32, scsh(3));   bnp(b11, N1, 32, nullptr, FAh, 4, true);
  knn(kp1, bsA + 0, N1, FAh, 32, 4, 0);
  convh(FAh, nbrs2, 4, N2, 32, 64, scsh(4));  bnp(bd1, N2, 64, nullptr, FBh, 5, true);
  convh(FBh, nbr2, 5, N2, 64, 64, scsh(5));   bnp(b20, N2, 64, nullptr, FAh, 6, true);
  convh(FAh, nbr2, 6, N2, 64, 64, scsh(6));   bnp(b21, N2, 64, nullptr, FBh, 7, true);
  convh(FBh, nbr2, 7, N2, 64, 64, scsh(7));   bnp(b22, N2, 64, nullptr, FAh, 8, true);
  knn(kp2, bsA + 1, N2, FAh, 64, 8, 32);
  convh(FAh, nbrs3, 8, N3, 64, 64, scsh(8));  bnp(bd2, N3, 64, nullptr, FBh, 9, true);
  convh(FBh, nbr3, 9, N3, 64, 64, scsh(9));   bnp(b30, N3, 64, nullptr, FAh, 10, true);
  convh(FAh, nbr3, 10, N3, 64, 64, scsh(10)); bnp(b31, N3, 64, nullptr, FBh, 11, true);
  convh(FBh, nbr3, 11, N3, 64, 64, scsh(11)); bnp(b32, N3, 64, nullptr, FAh, 12, true);
  knn(kp3, bsA + 2, N3, FAh, 64, 12, 96);

  conv1x1_k<<<cdiv(N3, 4), 256, 0, stream>>>(FAh, scsh(12), we, N3, FC);
  bn_k<false><<<NCH, 256, 0, stream>>>(FC, 1, 0, N3, 64, FB, FBh, stats, be, scsh(13),
                                       ctrs + 13);
  hipMemsetAsync(d_out, 0, (size_t)7680000 * 4, stream);
  scatter_k<<<cdiv(N3 * 64, 256), 256, 0, stream>>>(FB, scsh(13), c3, N3, out0);
  head_k<<<cdiv(N0, 4), 256, 0, stream>>>(X, fcw, clsw, regw, N0, outc, outr);
}

// Round 19
// 845.755 us; speedup vs baseline: 1.1632x; 1.0239x over previous
//
#include <hip/hip_runtime.h>

#define OFFX 0.0f
#define OFFY -40.0f
#define OFFZ -3.0f
#define BNEPS 1e-3f
#define NCH 128   // bn partial chunks
#define NG 9      // conv tap groups (3 taps each)

typedef _Float16 h2_t __attribute__((ext_vector_type(2)));
__device__ inline h2_t u2h(unsigned u) { union { unsigned u; h2_t h; } x; x.u = u; return x.h; }
__device__ inline unsigned h2u(h2_t h) { union { unsigned u; h2_t h; } x; x.h = h; return x.u; }

// ---------------- fused prep: keys x4, knn points x3 (+batch boundary), points_mean ----------------
struct PrepA {
  const int *c0, *c1, *c2, *c3;
  int n0, n1, n2, n3;
  int *k0, *k1, *k2, *k3;
  float4 *kp1, *kp2, *kp3;
  int* bs;
  const float* vf; float* pmb; float* out1;
};
__global__ void prep_k(PrepA a) {
  int i = blockIdx.x * 256 + threadIdx.x;
  if (i < a.n0) {
    const int* c = a.c0 + (size_t)i * 4;
    a.k0[i] = ((c[0] * 41 + c[1]) * 800 + c[2]) * 800 + c[3];
    float b = (float)c[0];
    float x = a.vf[(size_t)i * 4], y = a.vf[(size_t)i * 4 + 1], z = a.vf[(size_t)i * 4 + 2];
    a.pmb[(size_t)i * 4] = b; a.pmb[(size_t)i * 4 + 1] = x;
    a.pmb[(size_t)i * 4 + 2] = y; a.pmb[(size_t)i * 4 + 3] = z;
    a.out1[(size_t)i * 4] = b; a.out1[(size_t)i * 4 + 1] = x;
    a.out1[(size_t)i * 4 + 2] = y; a.out1[(size_t)i * 4 + 3] = z;
  }
  if (i < a.n1) {
    const int* c = a.c1 + (size_t)i * 4;
    a.k1[i] = ((c[0] * 21 + c[1]) * 400 + c[2]) * 400 + c[3];
    a.kp1[i] = make_float4(OFFX + (c[3] + 0.5f) * 0.2f, OFFY + (c[2] + 0.5f) * 0.2f,
                           OFFZ + (c[1] + 0.5f) * 0.4f, (float)c[0]);
    if (c[0] == 0 && (i + 1 == a.n1 || a.c1[(size_t)(i + 1) * 4] == 1)) a.bs[0] = i + 1;
  }
  if (i < a.n2) {
    const int* c = a.c2 + (size_t)i * 4;
    a.k2[i] = ((c[0] * 11 + c[1]) * 200 + c[2]) * 200 + c[3];
    a.kp2[i] = make_float4(OFFX + (c[3] + 0.5f) * 0.4f, OFFY + (c[2] + 0.5f) * 0.4f,
                           OFFZ + (c[1] + 0.5f) * 0.8f, (float)c[0]);
    if (c[0] == 0 && (i + 1 == a.n2 || a.c2[(size_t)(i + 1) * 4] == 1)) a.bs[1] = i + 1;
  }
  if (i < a.n3) {
    const int* c = a.c3 + (size_t)i * 4;
    a.k3[i] = ((c[0] * 6 + c[1]) * 100 + c[2]) * 100 + c[3];
    a.kp3[i] = make_float4(OFFX + (c[3] + 0.5f) * 0.8f, OFFY + (c[2] + 0.5f) * 0.8f,
                           OFFZ + (c[1] + 0.5f) * 1.6f, (float)c[0]);
    if (c[0] == 0 && (i + 1 == a.n3 || a.c3[(size_t)(i + 1) * 4] == 1)) a.bs[2] = i + 1;
  }
}

// ---------------- neighbor tables: one search per x-run of 3 consecutive keys ----------------
__global__ void nbr_k(const int* __restrict__ coords, int np, const int* __restrict__ keys, int nk,
                      int D, int H, int W, int scale, int* __restrict__ nbr) {
  int t = blockIdx.x * 256 + threadIdx.x;
  if (t >= np * 9) return;
  int p = t / 9, j = t % 9;
  int kz = j / 3 - 1, ky = j % 3 - 1;
  const int* c = coords + (size_t)p * 4;
  int z = c[1] * scale + kz, y = c[2] * scale + ky;
  int xb = c[3] * scale - 1;   // queries xb, xb+1, xb+2
  int r[3] = {-1, -1, -1};
  if (z >= 0 && z < D && y >= 0 && y < H) {
    int qb = ((c[0] * D + z) * H + y) * W + xb;  // monotone even if xb==-1
    int lo = 0, hi = nk;
    while (lo < hi) { int m = (lo + hi) >> 1; if (keys[m] < qb) lo = m + 1; else hi = m; }
#pragma unroll
    for (int dx = 0; dx < 3; dx++) {
      int q = qb + dx;
      int xq = xb + dx;
      if (lo < nk && keys[lo] == q) {
        if (xq >= 0 && xq < W) r[dx] = lo;
        lo++;
      }
    }
  }
  int* dst = nbr + (size_t)p * 27 + j * 3;
  dst[0] = r[0]; dst[1] = r[1]; dst[2] = r[2];
}

// ---------------- weight prep: fp32 [27][CIN][COUT] -> h2 [27][CIN/2][COUT] ----------------
struct WPrep { const float* src; unsigned* dst; int cin; int cout; };
struct WP13 { WPrep l[13]; };
__global__ void wprep_k(WP13 a) {
  WPrep w = a.l[blockIdx.y];
  int cp2 = w.cin / 2;
  int tot = 27 * cp2 * w.cout;
  int i = blockIdx.x * 256 + threadIdx.x;
  if (i >= tot) return;
  int o = i % w.cout, rest = i / w.cout;
  int cp = rest % cp2, k = rest / cp2;
  float lo = w.src[((size_t)k * w.cin + 2 * cp) * w.cout + o];
  float hi = w.src[((size_t)k * w.cin + 2 * cp + 1) * w.cout + o];
  h2_t h; h[0] = (_Float16)lo; h[1] = (_Float16)hi;
  w.dst[i] = h2u(h);
}

// ---------------- layer-0 conv (fp32, CIN=4): LDS tile-GEMM TP=32 ----------------
template<int CIN, int COUT>
__global__ __launch_bounds__(128) void convg_k(const float* __restrict__ feats,
                                               const int* __restrict__ nbr,
                                               const float* __restrict__ w, int n,
                                               float* __restrict__ partial, int gstride) {
  constexpr int TP = 32;
  constexpr int LDP = 36;
  constexpr int CO = COUT / 16;
  __shared__ float G[CIN * LDP];
  int tid = threadIdx.x;
  int pg = tid >> 4, cg = tid & 15;
  int p0 = blockIdx.x * TP;
  int k0 = blockIdx.y * 3;
  float acc[4][CO];
#pragma unroll
  for (int i = 0; i < 4; i++)
#pragma unroll
    for (int j = 0; j < CO; j++) acc[i][j] = 0.f;

  for (int kk = 0; kk < 3; kk++) {
    int k = k0 + kk;
    __syncthreads();
    for (int ch = tid; ch < TP * CIN / 4; ch += 128) {
      int r = ch & (TP - 1), c4 = ch / TP;
      int p = p0 + r;
      int idx = (p < n) ? nbr[(size_t)p * 27 + k] : -1;
      float4 fv = make_float4(0.f, 0.f, 0.f, 0.f);
      if (idx >= 0) fv = *(const float4*)(feats + (size_t)idx * CIN + c4 * 4);
      G[(c4 * 4 + 0) * LDP + r] = fv.x;
      G[(c4 * 4 + 1) * LDP + r] = fv.y;
      G[(c4 * 4 + 2) * LDP + r] = fv.z;
      G[(c4 * 4 + 3) * LDP + r] = fv.w;
    }
    __syncthreads();
    const float* wk = w + (size_t)k * CIN * COUT + cg * CO;
#pragma unroll
    for (int c = 0; c < CIN; c++) {
      float4 g4 = *(const float4*)&G[c * LDP + pg * 4];
      float wv[CO];
      if constexpr (CO == 4)      *(float4*)wv = *(const float4*)(wk + c * COUT);
      else if constexpr (CO == 2) *(float2*)wv = *(const float2*)(wk + c * COUT);
      else                        wv[0] = wk[c * COUT];
      float gp[4] = {g4.x, g4.y, g4.z, g4.w};
#pragma unroll
      for (int i = 0; i < 4; i++)
#pragma unroll
        for (int j = 0; j < CO; j++) acc[i][j] = fmaf(gp[i], wv[j], acc[i][j]);
    }
  }
#pragma unroll
  for (int i = 0; i < 4; i++) {
    int p = p0 + pg * 4 + i;
    if (p < n) {
      float* dst = partial + (size_t)blockIdx.y * gstride + (size_t)p * COUT + cg * CO;
      if constexpr (CO == 4)      *(float4*)dst = *(float4*)acc[i];
      else if constexpr (CO == 2) *(float2*)dst = *(float2*)acc[i];
      else                        dst[0] = acc[i][0];
    }
  }
}

// ---------------- f16 conv: software-pipelined gather, fdot2, fused BN+ReLU.
// Partials h2-packed when CO>=2; fp32 when CO==1. ----------------
template<int CIN, int COUT>
__global__ __launch_bounds__(128) void convh_k(const unsigned* __restrict__ fh,
                                               const int* __restrict__ nbr,
                                               const unsigned* __restrict__ wh, int n,
                                               void* __restrict__ partial, int gstride,
                                               const float* __restrict__ scsh) {
  constexpr int TP = 32;
  constexpr int LDPH = 36;
  constexpr int CO = COUT / 16;
  constexpr int CP = CIN / 2;
  constexpr bool H2P = (CO >= 2);
  __shared__ unsigned H[CP * LDPH];
  int tid = threadIdx.x;
  int pg = tid >> 4, cg = tid & 15;
  int p0 = blockIdx.x * TP;
  int k0 = blockIdx.y * 3;
  int r = tid & 31;
  int p = p0 + r;
  int sidx[3];
  if (p < n) {
    const int* nb = nbr + (size_t)p * 27 + k0;
    sidx[0] = nb[0]; sidx[1] = nb[1]; sidx[2] = nb[2];
  } else { sidx[0] = sidx[1] = sidx[2] = -1; }

  float acc[4][CO];
#pragma unroll
  for (int i = 0; i < 4; i++)
#pragma unroll
    for (int j = 0; j < CO; j++) acc[i][j] = 0.f;

  if constexpr (CIN >= 32) {
    constexpr int NLD = CIN / 32;
    uint4 pf[NLD];
    {
      int idx = sidx[0];
#pragma unroll
      for (int it = 0; it < NLD; it++) {
        int q = (tid >> 5) + it * 4;
        pf[it] = (idx >= 0) ? *(const uint4*)(fh + (size_t)idx * CP + q * 4)
                            : make_uint4(0, 0, 0, 0);
      }
    }
    for (int kk = 0; kk < 3; kk++) {
      bool ok = sidx[kk] >= 0;
      __syncthreads();
#pragma unroll
      for (int it = 0; it < NLD; it++) {
        int q = (tid >> 5) + it * 4;
        unsigned uu[4] = {pf[it].x, pf[it].y, pf[it].z, pf[it].w};
#pragma unroll
        for (int j = 0; j < 4; j++) {
          int cp = q * 4 + j;
          unsigned outw = 0;
          if (ok) {
            h2_t h = u2h(uu[j]);
            float lo = fmaxf(fmaf((float)h[0], scsh[2 * cp], scsh[CIN + 2 * cp]), 0.f);
            float hi = fmaxf(fmaf((float)h[1], scsh[2 * cp + 1], scsh[CIN + 2 * cp + 1]), 0.f);
            h2_t o; o[0] = (_Float16)lo; o[1] = (_Float16)hi;
            outw = h2u(o);
          }
          H[cp * LDPH + r] = outw;
        }
      }
      if (kk < 2) {
        int idx = sidx[kk + 1];
#pragma unroll
        for (int it = 0; it < NLD; it++) {
          int q = (tid >> 5) + it * 4;
          pf[it] = (idx >= 0) ? *(const uint4*)(fh + (size_t)idx * CP + q * 4)
                              : make_uint4(0, 0, 0, 0);
        }
      }
      __syncthreads();
      const unsigned* wk = wh + (size_t)(k0 + kk) * CP * COUT + cg * CO;
#pragma unroll 8
      for (int cp = 0; cp < CP; cp++) {
        uint4 g4 = *(const uint4*)&H[cp * LDPH + pg * 4];
        unsigned gg[4] = {g4.x, g4.y, g4.z, g4.w};
        unsigned wv[CO];
        if constexpr (CO == 4)      *(uint4*)wv = *(const uint4*)(wk + cp * COUT);
        else if constexpr (CO == 2) *(uint2*)wv = *(const uint2*)(wk + cp * COUT);
        else                        wv[0] = wk[cp * COUT];
#pragma unroll
        for (int i = 0; i < 4; i++)
#pragma unroll
          for (int j = 0; j < CO; j++)
            acc[i][j] = __builtin_amdgcn_fdot2(u2h(gg[i]), u2h(wv[j]), acc[i][j], false);
      }
    }
  } else {  // CIN == 16
    int q = tid >> 5;
    uint2 pf2;
    {
      int idx = sidx[0];
      pf2 = (idx >= 0) ? *(const uint2*)(fh + (size_t)idx * CP + q * 2) : make_uint2(0, 0);
    }
    for (int kk = 0; kk < 3; kk++) {
      bool ok = sidx[kk] >= 0;
      __syncthreads();
      unsigned uu[2] = {pf2.x, pf2.y};
#pragma unroll
      for (int j = 0; j < 2; j++) {
        int cp = q * 2 + j;
        unsigned outw = 0;
        if (ok) {
          h2_t h = u2h(uu[j]);
          float lo = fmaxf(fmaf((float)h[0], scsh[2 * cp], scsh[CIN + 2 * cp]), 0.f);
          float hi = fmaxf(fmaf((float)h[1], scsh[2 * cp + 1], scsh[CIN + 2 * cp + 1]), 0.f);
          h2_t o; o[0] = (_Float16)lo; o[1] = (_Float16)hi;
          outw = h2u(o);
        }
        H[cp * LDPH + r] = outw;
      }
      if (kk < 2) {
        int idx = sidx[kk + 1];
        pf2 = (idx >= 0) ? *(const uint2*)(fh + (size_t)idx * CP + q * 2) : make_uint2(0, 0);
      }
      __syncthreads();
      const unsigned* wk = wh + (size_t)(k0 + kk) * CP * COUT + cg * CO;
#pragma unroll
      for (int cp = 0; cp < CP; cp++) {
        uint4 g4 = *(const uint4*)&H[cp * LDPH + pg * 4];
        unsigned gg[4] = {g4.x, g4.y, g4.z, g4.w};
        unsigned wv[CO];
        if constexpr (CO == 4)      *(uint4*)wv = *(const uint4*)(wk + cp * COUT);
        else if constexpr (CO == 2) *(uint2*)wv = *(const uint2*)(wk + cp * COUT);
        else                        wv[0] = wk[cp * COUT];
#pragma unroll
        for (int i = 0; i < 4; i++)
#pragma unroll
          for (int j = 0; j < CO; j++)
            acc[i][j] = __builtin_amdgcn_fdot2(u2h(gg[i]), u2h(wv[j]), acc[i][j], false);
      }
    }
  }
#pragma unroll
  for (int i = 0; i < 4; i++) {
    int pp = p0 + pg * 4 + i;
    if (pp < n) {
      if constexpr (H2P) {
        unsigned* dst = (unsigned*)partial + (size_t)blockIdx.y * gstride
                      + (size_t)pp * (COUT / 2) + cg * (CO / 2);
        if constexpr (CO == 4) {
          h2_t a; a[0] = (_Float16)acc[i][0]; a[1] = (_Float16)acc[i][1];
          h2_t b; b[0] = (_Float16)acc[i][2]; b[1] = (_Float16)acc[i][3];
          *(uint2*)dst = make_uint2(h2u(a), h2u(b));
        } else {
          h2_t a; a[0] = (_Float16)acc[i][0]; a[1] = (_Float16)acc[i][1];
          dst[0] = h2u(a);
        }
      } else {
        float* dst = (float*)partial + (size_t)blockIdx.y * gstride
                   + (size_t)pp * COUT + cg * CO;
        dst[0] = acc[i][0];
      }
    }
  }
}

// ---------------- bn: sum partials -> preh (+opt fp32) + stats; last block finalizes ----------------
template<bool H2P>
__global__ void bn_k(const void* __restrict__ partial, int G, int gstride, int n, int C,
                     float* __restrict__ pre, unsigned* __restrict__ preh,
                     float* __restrict__ stats, const float* __restrict__ bnp,
                     float* __restrict__ scsh, int* __restrict__ ctr) {
  __shared__ float l1e[256], l2e[256], l1o[256], l2o[256];
  __shared__ int lastf;
  int t = threadIdx.x;
  int total = n * C;
  float s1e = 0.f, s2e = 0.f, s1o = 0.f, s2o = 0.f;
  for (int i2 = (blockIdx.x * 256 + t) * 2; i2 < total; i2 += NCH * 512) {
    float v0 = 0.f, v1 = 0.f;
    if constexpr (H2P) {
      const unsigned* ph = (const unsigned*)partial;
      for (int g = 0; g < G; g++) {
        h2_t h = u2h(ph[(size_t)g * gstride + (i2 >> 1)]);
        v0 += (float)h[0]; v1 += (float)h[1];
      }
    } else {
      const float* pf = (const float*)partial;
      for (int g = 0; g < G; g++) {
        float2 pv = *(const float2*)(pf + (size_t)g * gstride + i2);
        v0 += pv.x; v1 += pv.y;
      }
    }
    if (pre) *(float2*)(pre + i2) = make_float2(v0, v1);
    h2_t h; h[0] = (_Float16)v0; h[1] = (_Float16)v1;
    preh[i2 >> 1] = h2u(h);
    s1e += v0; s2e += v0 * v0; s1o += v1; s2o += v1 * v1;
  }
  l1e[t] = s1e; l2e[t] = s2e; l1o[t] = s1o; l2o[t] = s2o;
  for (int s = 128; s >= C / 2; s >>= 1) {
    __syncthreads();
    if (t < s) {
      l1e[t] += l1e[t + s]; l2e[t] += l2e[t + s];
      l1o[t] += l1o[t + s]; l2o[t] += l2o[t + s];
    }
  }
  __syncthreads();
  if (t < C / 2) {
    stats[((size_t)blockIdx.x * C + 2 * t) * 2]     = l1e[t];
    stats[((size_t)blockIdx.x * C + 2 * t) * 2 + 1] = l2e[t];
    stats[((size_t)blockIdx.x * C + 2 * t + 1) * 2]     = l1o[t];
    stats[((size_t)blockIdx.x * C + 2 * t + 1) * 2 + 1] = l2o[t];
  }
  __threadfence();
  __syncthreads();
  if (t == 0) lastf = (atomicAdd(ctr, 1) == NCH - 1) ? 1 : 0;
  __syncthreads();
  if (lastf) {
    __threadfence();
    int c = t % C, sub = t / C;
    int TPC = 256 / C;
    float a1 = 0.f, a2 = 0.f;
    for (int ch = sub; ch < NCH; ch += TPC) {
      a1 += stats[((size_t)ch * C + c) * 2];
      a2 += stats[((size_t)ch * C + c) * 2 + 1];
    }
    l1e[t] = a1; l2e[t] = a2;
    for (int s = 128; s >= C; s >>= 1) {
      __syncthreads();
      if (t < s) { l1e[t] += l1e[t + s]; l2e[t] += l2e[t + s]; }
    }
    __syncthreads();
    if (t < C) {
      float m = l1e[t] / n;
      float v = l2e[t] / n - m * m;
      float sc = bnp[t] / sqrtf(v + BNEPS);
      scsh[t] = sc;
      scsh[C + t] = bnp[C + t] - m * sc;
    }
  }
}

// ---------------- 3-NN + fused interp: 4 waves/block share LDS chunks; wave per unknown;
// after merge, lanes gather 3 h2 feature rows (BN+ReLU) and write X directly ----------------
__global__ __launch_bounds__(256) void knni_k(const float4* __restrict__ pm4, int n0,
                                              const float4* __restrict__ kp4, int nl,
                                              const int* __restrict__ bsp,
                                              const unsigned* __restrict__ fh, int C,
                                              const float* __restrict__ scsh,
                                              float* __restrict__ X, int xoff) {
  __shared__ __align__(16) float4 kp[256];
  __shared__ int bl[4], bh[4];
  int tid = threadIdx.x;
  int wave = tid >> 6, lane = tid & 63;
  int u = blockIdx.x * 4 + wave;
  bool valid = u < n0;
  float4 up = pm4[valid ? u : (n0 - 1)];
  int bs = bsp[0];
  int lo = (up.x == 0.f) ? 0 : bs;
  int hi = (up.x == 0.f) ? bs : nl;
  if (!valid) { lo = 0; hi = 0; }
  if (lane == 0) { bl[wave] = valid ? lo : 0x7fffffff; bh[wave] = valid ? hi : 0; }
  __syncthreads();
  int blo = min(min(bl[0], bl[1]), min(bl[2], bl[3]));
  int bhi = max(max(bh[0], bh[1]), max(bh[2], bh[3]));
  float ux = up.y, uy = up.z, uz = up.w;
  float d0 = 3e38f, d1 = 3e38f, d2 = 3e38f;
  int i0 = -1, i1 = -1, i2 = -1;
#define INS1(DD, GI) { \
    bool l0 = (DD) < d0, l1 = (DD) < d1, l2 = (DD) < d2; \
    i2 = l2 ? (l1 ? i1 : (GI)) : i2; \
    i1 = l1 ? (l0 ? i0 : (GI)) : i1; \
    i0 = l0 ? (GI) : i0; \
    float t1_ = __builtin_amdgcn_fmed3f(d0, d1, (DD)); \
    float t2_ = __builtin_amdgcn_fmed3f(d1, d2, (DD)); \
    d0 = fminf(d0, (DD)); d1 = t1_; d2 = t2_; }
#define DIST(Q) fmaf(ux - (Q).x, ux - (Q).x, fmaf(uy - (Q).y, uy - (Q).y, (uz - (Q).z) * (uz - (Q).z)))
  for (int cb = blo; cb < bhi; cb += 256) {
    int m = bhi - cb; if (m > 256) m = 256;
    __syncthreads();
    if (tid < m) kp[tid] = kp4[cb + tid];
    __syncthreads();
    if (cb + 256 <= lo || cb >= hi) continue;
    if (m == 256 && cb >= lo && cb + 256 <= hi) {
      float4 q0 = kp[lane], q1 = kp[lane + 64], q2 = kp[lane + 128], q3 = kp[lane + 192];
      float a0 = DIST(q0), a1 = DIST(q1), a2 = DIST(q2), a3 = DIST(q3);
      if (__any((a0 < d2) | (a1 < d2) | (a2 < d2) | (a3 < d2))) {
        INS1(a0, cb + lane) INS1(a1, cb + lane + 64)
        INS1(a2, cb + lane + 128) INS1(a3, cb + lane + 192)
      }
    } else {
#pragma unroll
      for (int j = 0; j < 4; j++) {
        int i = lane + 64 * j;
        int e = cb + i;
        if (i < m && e >= lo && e < hi) {
          float4 q = kp[i];
          float dd = DIST(q);
          INS1(dd, e)
        }
      }
    }
  }
#pragma unroll
  for (int off = 1; off < 64; off <<= 1) {
    float e0 = __shfl_xor(d0, off), e1 = __shfl_xor(d1, off), e2 = __shfl_xor(d2, off);
    int j0 = __shfl_xor(i0, off), j1 = __shfl_xor(i1, off), j2 = __shfl_xor(i2, off);
    INS1(e0, j0) INS1(e1, j1) INS1(e2, j2)
  }
#undef DIST
#undef INS1
  // broadcast lane-0 result (kill tie-order divergence across lanes)
  i0 = __shfl(i0, 0); i1 = __shfl(i1, 0); i2 = __shfl(i2, 0);
  d0 = __shfl(d0, 0); d1 = __shfl(d1, 0); d2 = __shfl(d2, 0);
  if (valid && i0 >= 0) {
    float w0 = 1.f / (d0 + 1e-8f), w1 = 1.f / (d1 + 1e-8f), w2 = 1.f / (d2 + 1e-8f);
    float s = w0 + w1 + w2;
    w0 /= s; w1 /= s; w2 /= s;
    int CP = C >> 1;
    for (int cp = lane; cp < CP; cp += 64) {
      h2_t h0 = u2h(fh[(size_t)i0 * CP + cp]);
      h2_t h1 = u2h(fh[(size_t)i1 * CP + cp]);
      h2_t h2v = u2h(fh[(size_t)i2 * CP + cp]);
      int ce = 2 * cp, co = 2 * cp + 1;
      float se = scsh[ce], he = scsh[C + ce];
      float so = scsh[co], ho = scsh[C + co];
      float ae = w0 * fmaxf(fmaf((float)h0[0], se, he), 0.f)
               + w1 * fmaxf(fmaf((float)h1[0], se, he), 0.f)
               + w2 * fmaxf(fmaf((float)h2v[0], se, he), 0.f);
      float ao = w0 * fmaxf(fmaf((float)h0[1], so, ho), 0.f)
               + w1 * fmaxf(fmaf((float)h1[1], so, ho), 0.f)
               + w2 * fmaxf(fmaf((float)h2v[1], so, ho), 0.f);
      *(float2*)(X + (size_t)u * 160 + xoff + ce) = make_float2(ae, ao);
    }
  }
}

// ---------------- extra 1x1 conv, h2 input with fused BN ----------------
__global__ __launch_bounds__(256) void conv1x1_k(const unsigned* __restrict__ fh,
                                                 const float* __restrict__ scsh,
                                                 const float* __restrict__ we, int n,
                                                 float* __restrict__ out) {
  __shared__ float rows[256];
  int t = threadIdx.x;
  int p = blockIdx.x * 4 + (t >> 6), c = t & 63;
  float v = 0.f;
  if (p < n) {
    h2_t h = u2h(fh[(size_t)p * 32 + (c >> 1)]);
    v = fmaxf(fmaf((float)h[c & 1], scsh[c], scsh[64 + c]), 0.f);
  }
  rows[t] = v;
  __syncthreads();
  if (p >= n) return;
  const float* fr = rows + (t >> 6) * 64;
  float a = 0.f;
#pragma unroll 16
  for (int ci = 0; ci < 64; ci++) a = fmaf(fr[ci], we[ci * 64 + c], a);
  out[(size_t)p * 64 + c] = a;
}

// ---------------- dense scatter with fused BN+ReLU ----------------
__global__ void scatter_k(const float* __restrict__ pre, const float* __restrict__ scsh,
                          const int* __restrict__ c3, int n3, float* __restrict__ out0) {
  int t = blockIdx.x * 256 + threadIdx.x;
  if (t >= n3 * 64) return;
  int p = t >> 6, c = t & 63;
  const int* cc = c3 + (size_t)p * 4;
  size_t o = ((((size_t)cc[0] * 64 + c) * 6 + cc[1]) * 100 + cc[2]) * 100 + cc[3];
  out0[o] = fmaxf(fmaf(pre[t], scsh[c], scsh[64 + c]), 0.f);
}

// ---------------- head ----------------
__global__ __launch_bounds__(256) void head_k(const float* __restrict__ X,
                                              const float* __restrict__ fcw,
                                              const float* __restrict__ clsw,
                                              const float* __restrict__ regw,
                                              int n0, float* __restrict__ outc,
                                              float* __restrict__ outr) {
  __shared__ float fl[64 * 161];
  int t = threadIdx.x;
  for (int i = t; i < 64 * 160; i += 256) {
    int r = i / 160, c = i % 160;
    fl[r * 161 + c] = fcw[i];
  }
  __syncthreads();
  int wave = t >> 6, lane = t & 63;
  int u = blockIdx.x * 4 + wave;
  if (u >= n0) return;
  const float* xr = X + (size_t)u * 160;
  const float* wr = fl + (size_t)lane * 161;
  float a = 0.f;
#pragma unroll 8
  for (int i = 0; i < 160; i++) a = fmaf(xr[i], wr[i], a);
  float c = a * clsw[lane];
  float r0 = a * regw[lane], r1 = a * regw[64 + lane], r2 = a * regw[128 + lane];
  for (int off = 32; off; off >>= 1) {
    c  += __shfl_down(c, off);
    r0 += __shfl_down(r0, off);
    r1 += __shfl_down(r1, off);
    r2 += __shfl_down(r2, off);
  }
  if (lane == 0) {
    outc[u] = c;
    outr[(size_t)u * 3] = r0; outr[(size_t)u * 3 + 1] = r1; outr[(size_t)u * 3 + 2] = r2;
  }
}

// ---------------- host ----------------
extern "C" void kernel_launch(void* const* d_in, const int* in_sizes, int n_in,
                              void* d_out, int out_size, void* d_ws, size_t ws_size,
                              hipStream_t stream) {
  const float* vf  = (const float*)d_in[0];
  const int* c0 = (const int*)d_in[1];
  const int* c1 = (const int*)d_in[2];
  const int* c2 = (const int*)d_in[3];
  const int* c3 = (const int*)d_in[4];
  const float* w00 = (const float*)d_in[5];  const float* b00 = (const float*)d_in[6];
  const float* w01 = (const float*)d_in[7];  const float* b01 = (const float*)d_in[8];
  const float* wd0 = (const float*)d_in[9];  const float* bd0 = (const float*)d_in[10];
  const float* w10 = (const float*)d_in[11]; const float* b10 = (const float*)d_in[12];
  const float* w11 = (const float*)d_in[13]; const float* b11 = (const float*)d_in[14];
  const float* wd1 = (const float*)d_in[15]; const float* bd1 = (const float*)d_in[16];
  const float* w20 = (const float*)d_in[17]; const float* b20 = (const float*)d_in[18];
  const float* w21 = (const float*)d_in[19]; const float* b21 = (const float*)d_in[20];
  const float* w22 = (const float*)d_in[21]; const float* b22 = (const float*)d_in[22];
  const float* wd2 = (const float*)d_in[23]; const float* bd2 = (const float*)d_in[24];
  const float* w30 = (const float*)d_in[25]; const float* b30 = (const float*)d_in[26];
  const float* w31 = (const float*)d_in[27]; const float* b31 = (const float*)d_in[28];
  const float* w32 = (const float*)d_in[29]; const float* b32 = (const float*)d_in[30];
  const float* we  = (const float*)d_in[31]; const float* be  = (const float*)d_in[32];
  const float* fcw = (const float*)d_in[33];
  const float* clsw = (const float*)d_in[34];
  const float* regw = (const float*)d_in[35];

  int N0 = in_sizes[1] / 4, N1 = in_sizes[2] / 4, N2 = in_sizes[3] / 4, N3 = in_sizes[4] / 4;
  int maxN = N0; if (N1 > maxN) maxN = N1; if (N2 > maxN) maxN = N2; if (N3 > maxN) maxN = N3;

  auto cdiv = [](int a, int b) { return (a + b - 1) / b; };
  char* p = (char*)d_ws;
  auto alloc = [&](size_t bytes) { char* r = p; p += (bytes + 255) & ~(size_t)255; return r; };

  int* keys0 = (int*)alloc((size_t)N0 * 4);
  int* keys1 = (int*)alloc((size_t)N1 * 4);
  int* keys2 = (int*)alloc((size_t)N2 * 4);
  int* keys3 = (int*)alloc((size_t)N3 * 4);
  int* nbr0  = (int*)alloc((size_t)N0 * 27 * 4);
  int* nbrs1 = (int*)alloc((size_t)N1 * 27 * 4);
  int* nbr1  = (int*)alloc((size_t)N1 * 27 * 4);
  int* nbrs2 = (int*)alloc((size_t)N2 * 27 * 4);
  int* nbr2  = (int*)alloc((size_t)N2 * 27 * 4);
  int* nbrs3 = (int*)alloc((size_t)N3 * 27 * 4);
  int* nbr3  = (int*)alloc((size_t)N3 * 27 * 4);
  float* FB = (float*)alloc((size_t)maxN * 64 * 4);
  float* FC = (float*)alloc((size_t)maxN * 64 * 4);
  unsigned* FAh = (unsigned*)alloc((size_t)maxN * 32 * 4);
  unsigned* FBh = (unsigned*)alloc((size_t)maxN * 32 * 4);
  float* stats = (float*)alloc((size_t)NCH * 64 * 2 * 4);
  float* SC = (float*)alloc((size_t)15 * 128 * 4);
  int* ctrs = (int*)alloc(16 * 4);
  float* X  = (float*)alloc((size_t)N0 * 160 * 4);
  float* pmb = (float*)alloc((size_t)N0 * 4 * 4);
  float4* kp1 = (float4*)alloc((size_t)N1 * 16);
  float4* kp2 = (float4*)alloc((size_t)N2 * 16);
  float4* kp3 = (float4*)alloc((size_t)N3 * 16);
  int* bsA = (int*)alloc(32);
  unsigned* whbuf = (unsigned*)alloc((size_t)452736 * 4);

  float* out0 = (float*)d_out;
  float* out1 = out0 + 7680000;
  float* outc = out1 + (size_t)N0 * 4;
  float* outr = outc + N0;
  void* partial = out0;  // conv partial scratch until final memset

  auto scsh = [&](int L) { return SC + (size_t)L * 128; };

  const float* wsrc[13] = {w01, wd0, w10, w11, wd1, w20, w21, w22, wd2, w30, w31, w32, nullptr};
  int wcin[13]  = {16, 16, 32, 32, 32, 64, 64, 64, 64, 64, 64, 64, 0};
  int wcout[13] = {16, 32, 32, 32, 64, 64, 64, 64, 64, 64, 64, 64, 0};
  unsigned* wdst[13];
  size_t woff = 0;
  WP13 wp{};
  int nw = 12;
  for (int i = 0; i < nw; i++) {
    wdst[i] = whbuf + woff;
    wp.l[i] = WPrep{wsrc[i], wdst[i], wcin[i], wcout[i]};
    woff += (size_t)27 * (wcin[i] / 2) * wcout[i];
  }
  for (int i = nw; i < 13; i++) wp.l[i] = WPrep{w01, wdst[0], 16, 16};

  hipMemsetAsync(ctrs, 0, 16 * 4, stream);
  wprep_k<<<dim3(216, nw), 256, 0, stream>>>(wp);
  PrepA pa;
  pa.c0 = c0; pa.c1 = c1; pa.c2 = c2; pa.c3 = c3;
  pa.n0 = N0; pa.n1 = N1; pa.n2 = N2; pa.n3 = N3;
  pa.k0 = keys0; pa.k1 = keys1; pa.k2 = keys2; pa.k3 = keys3;
  pa.kp1 = kp1; pa.kp2 = kp2; pa.kp3 = kp3;
  pa.bs = bsA; pa.vf = vf; pa.pmb = pmb; pa.out1 = out1;
  prep_k<<<cdiv(maxN, 256), 256, 0, stream>>>(pa);
  nbr_k<<<cdiv(N0 * 9, 256), 256, 0, stream>>>(c0, N0, keys0, N0, 41, 800, 800, 1, nbr0);
  nbr_k<<<cdiv(N1 * 9, 256), 256, 0, stream>>>(c1, N1, keys0, N0, 41, 800, 800, 2, nbrs1);
  nbr_k<<<cdiv(N1 * 9, 256), 256, 0, stream>>>(c1, N1, keys1, N1, 21, 400, 400, 1, nbr1);
  nbr_k<<<cdiv(N2 * 9, 256), 256, 0, stream>>>(c2, N2, keys1, N1, 21, 400, 400, 2, nbrs2);
  nbr_k<<<cdiv(N2 * 9, 256), 256, 0, stream>>>(c2, N2, keys2, N2, 11, 200, 200, 1, nbr2);
  nbr_k<<<cdiv(N3 * 9, 256), 256, 0, stream>>>(c3, N3, keys2, N2, 11, 200, 200, 2, nbrs3);
  nbr_k<<<cdiv(N3 * 9, 256), 256, 0, stream>>>(c3, N3, keys3, N3, 6, 100, 100, 1, nbr3);

  auto convh = [&](const unsigned* fhin, const int* nb, int wi, int n, int cin, int cout,
                   const float* ss) {
    dim3 g(cdiv(n, 32), NG);
    int gs = (cout >= 32) ? n * cout / 2 : n * cout;  // uints when h2-packed
    const unsigned* wh = wdst[wi];
    if (cin == 16 && cout == 16)
      convh_k<16, 16><<<g, 128, 0, stream>>>(fhin, nb, wh, n, partial, gs, ss);
    else if (cin == 16 && cout == 32)
      convh_k<16, 32><<<g, 128, 0, stream>>>(fhin, nb, wh, n, partial, gs, ss);
    else if (cin == 32 && cout == 32)
      convh_k<32, 32><<<g, 128, 0, stream>>>(fhin, nb, wh, n, partial, gs, ss);
    else if (cin == 32 && cout == 64)
      convh_k<32, 64><<<g, 128, 0, stream>>>(fhin, nb, wh, n, partial, gs, ss);
    else
      convh_k<64, 64><<<g, 128, 0, stream>>>(fhin, nb, wh, n, partial, gs, ss);
  };
  auto bnp = [&](const float* bnpar, int n, int C, float* pre, unsigned* preh, int L, bool h2p) {
    int gs = h2p ? n * C / 2 : n * C;
    if (h2p)
      bn_k<true><<<NCH, 256, 0, stream>>>(partial, NG, gs, n, C, pre, preh, stats, bnpar,
                                          scsh(L), ctrs + L);
    else
      bn_k<false><<<NCH, 256, 0, stream>>>(partial, NG, gs, n, C, pre, preh, stats, bnpar,
                                           scsh(L), ctrs + L);
  };
  auto knn = [&](const float4* kp4, const int* bsl, int nl, const unsigned* fh, int C, int L,
                 int xoff) {
    knni_k<<<cdiv(N0, 4), 256, 0, stream>>>((const float4*)pmb, N0, kp4, nl, bsl,
                                            fh, C, scsh(L), X, xoff);
  };

  // layer 0: fp32 conv from raw voxel features
  convg_k<4, 16><<<dim3(cdiv(N0, 32), NG), 128, 0, stream>>>(vf, nbr0, w00, N0,
                                                             (float*)partial, N0 * 16);
  bnp(b00, N0, 16, nullptr, FAh, 0, false);
  convh(FAh, nbr0, 0, N0, 16, 16, scsh(0));   bnp(b01, N0, 16, nullptr, FBh, 1, false);
  convh(FBh, nbrs1, 1, N1, 16, 32, scsh(1));  bnp(bd0, N1, 32, nullptr, FAh, 2, true);
  convh(FAh, nbr1, 2, N1, 32, 32, scsh(2));   bnp(b10, N1, 32, nullptr, FBh, 3, true);
  convh(FBh, nbr1, 3, N1, 32, 32, scsh(3));   bnp(b11, N1, 32, nullptr, FAh, 4, true);
  knn(kp1, bsA + 0, N1, FAh, 32, 4, 0);
  convh(FAh, nbrs2, 4, N2, 32, 64, scsh(4));  bnp(bd1, N2, 64, nullptr, FBh, 5, true);
  convh(FBh, nbr2, 5, N2, 64, 64, scsh(5));   bnp(b20, N2, 64, nullptr, FAh, 6, true);
  convh(FAh, nbr2, 6, N2, 64, 64, scsh(6));   bnp(b21, N2, 64, nullptr, FBh, 7, true);
  convh(FBh, nbr2, 7, N2, 64, 64, scsh(7));   bnp(b22, N2, 64, nullptr, FAh, 8, true);
  knn(kp2, bsA + 1, N2, FAh, 64, 8, 32);
  convh(FAh, nbrs3, 8, N3, 64, 64, scsh(8));  bnp(bd2, N3, 64, nullptr, FBh, 9, true);
  convh(FBh, nbr3, 9, N3, 64, 64, scsh(9));   bnp(b30, N3, 64, nullptr, FAh, 10, true);
  convh(FAh, nbr3, 10, N3, 64, 64, scsh(10)); bnp(b31, N3, 64, nullptr, FBh, 11, true);
  convh(FBh, nbr3, 11, N3, 64, 64, scsh(11)); bnp(b32, N3, 64, nullptr, FAh, 12, true);
  knn(kp3, bsA + 2, N3, FAh, 64, 12, 96);

  conv1x1_k<<<cdiv(N3, 4), 256, 0, stream>>>(FAh, scsh(12), we, N3, FC);
  bn_k<false><<<NCH, 256, 0, stream>>>(FC, 1, 0, N3, 64, FB, FBh, stats, be, scsh(13),
                                       ctrs + 13);
  hipMemsetAsync(d_out, 0, (size_t)7680000 * 4, stream);
  scatter_k<<<cdiv(N3 * 64, 256), 256, 0, stream>>>(FB, scsh(13), c3, N3, out0);
  head_k<<<cdiv(N0, 4), 256, 0, stream>>>(X, fcw, clsw, regw, N0, outc, outr);
}

// Round 20
// 816.821 us; speedup vs baseline: 1.2044x; 1.0354x over previous
//
#include <hip/hip_runtime.h>

#define OFFX 0.0f
#define OFFY -40.0f
#define OFFZ -3.0f
#define BNEPS 1e-3f
#define NCH 128   // bn partial chunks
#define NG 9      // conv tap groups (3 taps each)

typedef _Float16 h2_t __attribute__((ext_vector_type(2)));
__device__ inline h2_t u2h(unsigned u) { union { unsigned u; h2_t h; } x; x.u = u; return x.h; }
__device__ inline unsigned h2u(h2_t h) { union { unsigned u; h2_t h; } x; x.h = h; return x.u; }

// ---------------- fused prep: keys x4, knn points x3 (+batch boundary), points_mean, ctr zero ----------------
struct PrepA {
  const int *c0, *c1, *c2, *c3;
  int n0, n1, n2, n3;
  int *k0, *k1, *k2, *k3;
  float4 *kp1, *kp2, *kp3;
  int* bs;
  const float* vf; float* pmb; float* out1;
  int* ctrs;
};
__global__ void prep_k(PrepA a) {
  int i = blockIdx.x * 256 + threadIdx.x;
  if (i < 16) a.ctrs[i] = 0;
  if (i < a.n0) {
    const int* c = a.c0 + (size_t)i * 4;
    a.k0[i] = ((c[0] * 41 + c[1]) * 800 + c[2]) * 800 + c[3];
    float b = (float)c[0];
    float x = a.vf[(size_t)i * 4], y = a.vf[(size_t)i * 4 + 1], z = a.vf[(size_t)i * 4 + 2];
    a.pmb[(size_t)i * 4] = b; a.pmb[(size_t)i * 4 + 1] = x;
    a.pmb[(size_t)i * 4 + 2] = y; a.pmb[(size_t)i * 4 + 3] = z;
    a.out1[(size_t)i * 4] = b; a.out1[(size_t)i * 4 + 1] = x;
    a.out1[(size_t)i * 4 + 2] = y; a.out1[(size_t)i * 4 + 3] = z;
  }
  if (i < a.n1) {
    const int* c = a.c1 + (size_t)i * 4;
    a.k1[i] = ((c[0] * 21 + c[1]) * 400 + c[2]) * 400 + c[3];
    a.kp1[i] = make_float4(OFFX + (c[3] + 0.5f) * 0.2f, OFFY + (c[2] + 0.5f) * 0.2f,
                           OFFZ + (c[1] + 0.5f) * 0.4f, (float)c[0]);
    if (c[0] == 0 && (i + 1 == a.n1 || a.c1[(size_t)(i + 1) * 4] == 1)) a.bs[0] = i + 1;
  }
  if (i < a.n2) {
    const int* c = a.c2 + (size_t)i * 4;
    a.k2[i] = ((c[0] * 11 + c[1]) * 200 + c[2]) * 200 + c[3];
    a.kp2[i] = make_float4(OFFX + (c[3] + 0.5f) * 0.4f, OFFY + (c[2] + 0.5f) * 0.4f,
                           OFFZ + (c[1] + 0.5f) * 0.8f, (float)c[0]);
    if (c[0] == 0 && (i + 1 == a.n2 || a.c2[(size_t)(i + 1) * 4] == 1)) a.bs[1] = i + 1;
  }
  if (i < a.n3) {
    const int* c = a.c3 + (size_t)i * 4;
    a.k3[i] = ((c[0] * 6 + c[1]) * 100 + c[2]) * 100 + c[3];
    a.kp3[i] = make_float4(OFFX + (c[3] + 0.5f) * 0.8f, OFFY + (c[2] + 0.5f) * 0.8f,
                           OFFZ + (c[1] + 0.5f) * 1.6f, (float)c[0]);
    if (c[0] == 0 && (i + 1 == a.n3 || a.c3[(size_t)(i + 1) * 4] == 1)) a.bs[2] = i + 1;
  }
}

// ---------------- batched neighbor tables: one search per x-run of 3 consecutive keys ----------------
struct NbrE { const int* coords; int np; const int* keys; int nk; int D, H, W, scale; int* nbr; };
struct NbrA { NbrE e[7]; };
__global__ void nbra_k(NbrA a) {
  NbrE v = a.e[blockIdx.y];
  int t = blockIdx.x * 256 + threadIdx.x;
  if (t >= v.np * 9) return;
  int p = t / 9, j = t % 9;
  int kz = j / 3 - 1, ky = j % 3 - 1;
  const int* c = v.coords + (size_t)p * 4;
  int z = c[1] * v.scale + kz, y = c[2] * v.scale + ky;
  int xb = c[3] * v.scale - 1;   // queries xb, xb+1, xb+2
  int r[3] = {-1, -1, -1};
  if (z >= 0 && z < v.D && y >= 0 && y < v.H) {
    int qb = ((c[0] * v.D + z) * v.H + y) * v.W + xb;  // monotone even if xb==-1
    int lo = 0, hi = v.nk;
    const int* keys = v.keys;
    while (lo < hi) { int m = (lo + hi) >> 1; if (keys[m] < qb) lo = m + 1; else hi = m; }
#pragma unroll
    for (int dx = 0; dx < 3; dx++) {
      int q = qb + dx;
      int xq = xb + dx;
      if (lo < v.nk && keys[lo] == q) {
        if (xq >= 0 && xq < v.W) r[dx] = lo;
        lo++;
      }
    }
  }
  int* dst = v.nbr + (size_t)p * 27 + j * 3;
  dst[0] = r[0]; dst[1] = r[1]; dst[2] = r[2];
}

// ---------------- weight prep: fp32 [27][CIN][COUT] -> h2 [27][CIN/2][COUT] ----------------
struct WPrep { const float* src; unsigned* dst; int cin; int cout; };
struct WP13 { WPrep l[13]; };
__global__ void wprep_k(WP13 a) {
  WPrep w = a.l[blockIdx.y];
  int cp2 = w.cin / 2;
  int tot = 27 * cp2 * w.cout;
  int i = blockIdx.x * 256 + threadIdx.x;
  if (i >= tot) return;
  int o = i % w.cout, rest = i / w.cout;
  int cp = rest % cp2, k = rest / cp2;
  float lo = w.src[((size_t)k * w.cin + 2 * cp) * w.cout + o];
  float hi = w.src[((size_t)k * w.cin + 2 * cp + 1) * w.cout + o];
  h2_t h; h[0] = (_Float16)lo; h[1] = (_Float16)hi;
  w.dst[i] = h2u(h);
}

// ---------------- layer-0 conv (fp32, CIN=4): LDS tile-GEMM TP=32 ----------------
template<int CIN, int COUT>
__global__ __launch_bounds__(128) void convg_k(const float* __restrict__ feats,
                                               const int* __restrict__ nbr,
                                               const float* __restrict__ w, int n,
                                               float* __restrict__ partial, int gstride) {
  constexpr int TP = 32;
  constexpr int LDP = 36;
  constexpr int CO = COUT / 16;
  __shared__ float G[CIN * LDP];
  int tid = threadIdx.x;
  int pg = tid >> 4, cg = tid & 15;
  int p0 = blockIdx.x * TP;
  int k0 = blockIdx.y * 3;
  float acc[4][CO];
#pragma unroll
  for (int i = 0; i < 4; i++)
#pragma unroll
    for (int j = 0; j < CO; j++) acc[i][j] = 0.f;

  for (int kk = 0; kk < 3; kk++) {
    int k = k0 + kk;
    __syncthreads();
    for (int ch = tid; ch < TP * CIN / 4; ch += 128) {
      int r = ch & (TP - 1), c4 = ch / TP;
      int p = p0 + r;
      int idx = (p < n) ? nbr[(size_t)p * 27 + k] : -1;
      float4 fv = make_float4(0.f, 0.f, 0.f, 0.f);
      if (idx >= 0) fv = *(const float4*)(feats + (size_t)idx * CIN + c4 * 4);
      G[(c4 * 4 + 0) * LDP + r] = fv.x;
      G[(c4 * 4 + 1) * LDP + r] = fv.y;
      G[(c4 * 4 + 2) * LDP + r] = fv.z;
      G[(c4 * 4 + 3) * LDP + r] = fv.w;
    }
    __syncthreads();
    const float* wk = w + (size_t)k * CIN * COUT + cg * CO;
#pragma unroll
    for (int c = 0; c < CIN; c++) {
      float4 g4 = *(const float4*)&G[c * LDP + pg * 4];
      float wv[CO];
      if constexpr (CO == 4)      *(float4*)wv = *(const float4*)(wk + c * COUT);
      else if constexpr (CO == 2) *(float2*)wv = *(const float2*)(wk + c * COUT);
      else                        wv[0] = wk[c * COUT];
      float gp[4] = {g4.x, g4.y, g4.z, g4.w};
#pragma unroll
      for (int i = 0; i < 4; i++)
#pragma unroll
        for (int j = 0; j < CO; j++) acc[i][j] = fmaf(gp[i], wv[j], acc[i][j]);
    }
  }
#pragma unroll
  for (int i = 0; i < 4; i++) {
    int p = p0 + pg * 4 + i;
    if (p < n) {
      float* dst = partial + (size_t)blockIdx.y * gstride + (size_t)p * COUT + cg * CO;
      if constexpr (CO == 4)      *(float4*)dst = *(float4*)acc[i];
      else if constexpr (CO == 2) *(float2*)dst = *(float2*)acc[i];
      else                        dst[0] = acc[i][0];
    }
  }
}

// ---------------- f16 conv: software-pipelined gather, fdot2, fused BN+ReLU.
// Partials h2-packed when CO>=2; fp32 when CO==1. ----------------
template<int CIN, int COUT>
__global__ __launch_bounds__(128) void convh_k(const unsigned* __restrict__ fh,
                                               const int* __restrict__ nbr,
                                               const unsigned* __restrict__ wh, int n,
                                               void* __restrict__ partial, int gstride,
                                               const float* __restrict__ scsh) {
  constexpr int TP = 32;
  constexpr int LDPH = 36;
  constexpr int CO = COUT / 16;
  constexpr int CP = CIN / 2;
  constexpr bool H2P = (CO >= 2);
  __shared__ unsigned H[CP * LDPH];
  int tid = threadIdx.x;
  int pg = tid >> 4, cg = tid & 15;
  int p0 = blockIdx.x * TP;
  int k0 = blockIdx.y * 3;
  int r = tid & 31;
  int p = p0 + r;
  int sidx[3];
  if (p < n) {
    const int* nb = nbr + (size_t)p * 27 + k0;
    sidx[0] = nb[0]; sidx[1] = nb[1]; sidx[2] = nb[2];
  } else { sidx[0] = sidx[1] = sidx[2] = -1; }

  float acc[4][CO];
#pragma unroll
  for (int i = 0; i < 4; i++)
#pragma unroll
    for (int j = 0; j < CO; j++) acc[i][j] = 0.f;

  if constexpr (CIN >= 32) {
    constexpr int NLD = CIN / 32;
    uint4 pf[NLD];
    {
      int idx = sidx[0];
#pragma unroll
      for (int it = 0; it < NLD; it++) {
        int q = (tid >> 5) + it * 4;
        pf[it] = (idx >= 0) ? *(const uint4*)(fh + (size_t)idx * CP + q * 4)
                            : make_uint4(0, 0, 0, 0);
      }
    }
    for (int kk = 0; kk < 3; kk++) {
      bool ok = sidx[kk] >= 0;
      __syncthreads();
#pragma unroll
      for (int it = 0; it < NLD; it++) {
        int q = (tid >> 5) + it * 4;
        unsigned uu[4] = {pf[it].x, pf[it].y, pf[it].z, pf[it].w};
#pragma unroll
        for (int j = 0; j < 4; j++) {
          int cp = q * 4 + j;
          unsigned outw = 0;
          if (ok) {
            h2_t h = u2h(uu[j]);
            float lo = fmaxf(fmaf((float)h[0], scsh[2 * cp], scsh[CIN + 2 * cp]), 0.f);
            float hi = fmaxf(fmaf((float)h[1], scsh[2 * cp + 1], scsh[CIN + 2 * cp + 1]), 0.f);
            h2_t o; o[0] = (_Float16)lo; o[1] = (_Float16)hi;
            outw = h2u(o);
          }
          H[cp * LDPH + r] = outw;
        }
      }
      if (kk < 2) {
        int idx = sidx[kk + 1];
#pragma unroll
        for (int it = 0; it < NLD; it++) {
          int q = (tid >> 5) + it * 4;
          pf[it] = (idx >= 0) ? *(const uint4*)(fh + (size_t)idx * CP + q * 4)
                              : make_uint4(0, 0, 0, 0);
        }
      }
      __syncthreads();
      const unsigned* wk = wh + (size_t)(k0 + kk) * CP * COUT + cg * CO;
#pragma unroll 8
      for (int cp = 0; cp < CP; cp++) {
        uint4 g4 = *(const uint4*)&H[cp * LDPH + pg * 4];
        unsigned gg[4] = {g4.x, g4.y, g4.z, g4.w};
        unsigned wv[CO];
        if constexpr (CO == 4)      *(uint4*)wv = *(const uint4*)(wk + cp * COUT);
        else if constexpr (CO == 2) *(uint2*)wv = *(const uint2*)(wk + cp * COUT);
        else                        wv[0] = wk[cp * COUT];
#pragma unroll
        for (int i = 0; i < 4; i++)
#pragma unroll
          for (int j = 0; j < CO; j++)
            acc[i][j] = __builtin_amdgcn_fdot2(u2h(gg[i]), u2h(wv[j]), acc[i][j], false);
      }
    }
  } else {  // CIN == 16
    int q = tid >> 5;
    uint2 pf2;
    {
      int idx = sidx[0];
      pf2 = (idx >= 0) ? *(const uint2*)(fh + (size_t)idx * CP + q * 2) : make_uint2(0, 0);
    }
    for (int kk = 0; kk < 3; kk++) {
      bool ok = sidx[kk] >= 0;
      __syncthreads();
      unsigned uu[2] = {pf2.x, pf2.y};
#pragma unroll
      for (int j = 0; j < 2; j++) {
        int cp = q * 2 + j;
        unsigned outw = 0;
        if (ok) {
          h2_t h = u2h(uu[j]);
          float lo = fmaxf(fmaf((float)h[0], scsh[2 * cp], scsh[CIN + 2 * cp]), 0.f);
          float hi = fmaxf(fmaf((float)h[1], scsh[2 * cp + 1], scsh[CIN + 2 * cp + 1]), 0.f);
          h2_t o; o[0] = (_Float16)lo; o[1] = (_Float16)hi;
          outw = h2u(o);
        }
        H[cp * LDPH + r] = outw;
      }
      if (kk < 2) {
        int idx = sidx[kk + 1];
        pf2 = (idx >= 0) ? *(const uint2*)(fh + (size_t)idx * CP + q * 2) : make_uint2(0, 0);
      }
      __syncthreads();
      const unsigned* wk = wh + (size_t)(k0 + kk) * CP * COUT + cg * CO;
#pragma unroll
      for (int cp = 0; cp < CP; cp++) {
        uint4 g4 = *(const uint4*)&H[cp * LDPH + pg * 4];
        unsigned gg[4] = {g4.x, g4.y, g4.z, g4.w};
        unsigned wv[CO];
        if constexpr (CO == 4)      *(uint4*)wv = *(const uint4*)(wk + cp * COUT);
        else if constexpr (CO == 2) *(uint2*)wv = *(const uint2*)(wk + cp * COUT);
        else                        wv[0] = wk[cp * COUT];
#pragma unroll
        for (int i = 0; i < 4; i++)
#pragma unroll
          for (int j = 0; j < CO; j++)
            acc[i][j] = __builtin_amdgcn_fdot2(u2h(gg[i]), u2h(wv[j]), acc[i][j], false);
      }
    }
  }
#pragma unroll
  for (int i = 0; i < 4; i++) {
    int pp = p0 + pg * 4 + i;
    if (pp < n) {
      if constexpr (H2P) {
        unsigned* dst = (unsigned*)partial + (size_t)blockIdx.y * gstride
                      + (size_t)pp * (COUT / 2) + cg * (CO / 2);
        if constexpr (CO == 4) {
          h2_t a; a[0] = (_Float16)acc[i][0]; a[1] = (_Float16)acc[i][1];
          h2_t b; b[0] = (_Float16)acc[i][2]; b[1] = (_Float16)acc[i][3];
          *(uint2*)dst = make_uint2(h2u(a), h2u(b));
        } else {
          h2_t a; a[0] = (_Float16)acc[i][0]; a[1] = (_Float16)acc[i][1];
          dst[0] = h2u(a);
        }
      } else {
        float* dst = (float*)partial + (size_t)blockIdx.y * gstride
                   + (size_t)pp * COUT + cg * CO;
        dst[0] = acc[i][0];
      }
    }
  }
}

// ---------------- bn: sum partials -> preh (+opt fp32) + stats; last block finalizes ----------------
template<bool H2P>
__global__ void bn_k(const void* __restrict__ partial, int G, int gstride, int n, int C,
                     float* __restrict__ pre, unsigned* __restrict__ preh,
                     float* __restrict__ stats, const float* __restrict__ bnp,
                     float* __restrict__ scsh, int* __restrict__ ctr) {
  __shared__ float l1e[256], l2e[256], l1o[256], l2o[256];
  __shared__ int lastf;
  int t = threadIdx.x;
  int total = n * C;
  float s1e = 0.f, s2e = 0.f, s1o = 0.f, s2o = 0.f;
  for (int i2 = (blockIdx.x * 256 + t) * 2; i2 < total; i2 += NCH * 512) {
    float v0 = 0.f, v1 = 0.f;
    if constexpr (H2P) {
      const unsigned* ph = (const unsigned*)partial;
      for (int g = 0; g < G; g++) {
        h2_t h = u2h(ph[(size_t)g * gstride + (i2 >> 1)]);
        v0 += (float)h[0]; v1 += (float)h[1];
      }
    } else {
      const float* pf = (const float*)partial;
      for (int g = 0; g < G; g++) {
        float2 pv = *(const float2*)(pf + (size_t)g * gstride + i2);
        v0 += pv.x; v1 += pv.y;
      }
    }
    if (pre) *(float2*)(pre + i2) = make_float2(v0, v1);
    h2_t h; h[0] = (_Float16)v0; h[1] = (_Float16)v1;
    preh[i2 >> 1] = h2u(h);
    s1e += v0; s2e += v0 * v0; s1o += v1; s2o += v1 * v1;
  }
  l1e[t] = s1e; l2e[t] = s2e; l1o[t] = s1o; l2o[t] = s2o;
  for (int s = 128; s >= C / 2; s >>= 1) {
    __syncthreads();
    if (t < s) {
      l1e[t] += l1e[t + s]; l2e[t] += l2e[t + s];
      l1o[t] += l1o[t + s]; l2o[t] += l2o[t + s];
    }
  }
  __syncthreads();
  if (t < C / 2) {
    stats[((size_t)blockIdx.x * C + 2 * t) * 2]     = l1e[t];
    stats[((size_t)blockIdx.x * C + 2 * t) * 2 + 1] = l2e[t];
    stats[((size_t)blockIdx.x * C + 2 * t + 1) * 2]     = l1o[t];
    stats[((size_t)blockIdx.x * C + 2 * t + 1) * 2 + 1] = l2o[t];
  }
  __threadfence();
  __syncthreads();
  if (t == 0) lastf = (atomicAdd(ctr, 1) == NCH - 1) ? 1 : 0;
  __syncthreads();
  if (lastf) {
    __threadfence();
    int c = t % C, sub = t / C;
    int TPC = 256 / C;
    float a1 = 0.f, a2 = 0.f;
    for (int ch = sub; ch < NCH; ch += TPC) {
      a1 += stats[((size_t)ch * C + c) * 2];
      a2 += stats[((size_t)ch * C + c) * 2 + 1];
    }
    l1e[t] = a1; l2e[t] = a2;
    for (int s = 128; s >= C; s >>= 1) {
      __syncthreads();
      if (t < s) { l1e[t] += l1e[t + s]; l2e[t] += l2e[t + s]; }
    }
    __syncthreads();
    if (t < C) {
      float m = l1e[t] / n;
      float v = l2e[t] / n - m * m;
      float sc = bnp[t] / sqrtf(v + BNEPS);
      scsh[t] = sc;
      scsh[C + t] = bnp[C + t] - m * sc;
    }
  }
}

// ---------------- 3-NN + fused interp: 4 waves/block share LDS chunks (512); wave per unknown ----------------
__global__ __launch_bounds__(256) void knni_k(const float4* __restrict__ pm4, int n0,
                                              const float4* __restrict__ kp4, int nl,
                                              const int* __restrict__ bsp,
                                              const unsigned* __restrict__ fh, int C,
                                              const float* __restrict__ scsh,
                                              float* __restrict__ X, int xoff) {
  __shared__ __align__(16) float4 kp[512];
  __shared__ int bl[4], bh[4];
  int tid = threadIdx.x;
  int wave = tid >> 6, lane = tid & 63;
  int u = blockIdx.x * 4 + wave;
  bool valid = u < n0;
  float4 up = pm4[valid ? u : (n0 - 1)];
  int bs = bsp[0];
  int lo = (up.x == 0.f) ? 0 : bs;
  int hi = (up.x == 0.f) ? bs : nl;
  if (!valid) { lo = 0; hi = 0; }
  if (lane == 0) { bl[wave] = valid ? lo : 0x7fffffff; bh[wave] = valid ? hi : 0; }
  __syncthreads();
  int blo = min(min(bl[0], bl[1]), min(bl[2], bl[3]));
  int bhi = max(max(bh[0], bh[1]), max(bh[2], bh[3]));
  float ux = up.y, uy = up.z, uz = up.w;
  float d0 = 3e38f, d1 = 3e38f, d2 = 3e38f;
  int i0 = -1, i1 = -1, i2 = -1;
#define INS1(DD, GI) { \
    bool l0 = (DD) < d0, l1 = (DD) < d1, l2 = (DD) < d2; \
    i2 = l2 ? (l1 ? i1 : (GI)) : i2; \
    i1 = l1 ? (l0 ? i0 : (GI)) : i1; \
    i0 = l0 ? (GI) : i0; \
    float t1_ = __builtin_amdgcn_fmed3f(d0, d1, (DD)); \
    float t2_ = __builtin_amdgcn_fmed3f(d1, d2, (DD)); \
    d0 = fminf(d0, (DD)); d1 = t1_; d2 = t2_; }
#define DIST(Q) fmaf(ux - (Q).x, ux - (Q).x, fmaf(uy - (Q).y, uy - (Q).y, (uz - (Q).z) * (uz - (Q).z)))
  for (int cb = blo; cb < bhi; cb += 512) {
    int m = bhi - cb; if (m > 512) m = 512;
    __syncthreads();
    for (int i = tid; i < m; i += 256) kp[i] = kp4[cb + i];
    __syncthreads();
    if (cb + 512 <= lo || cb >= hi) continue;
    if (m == 512 && cb >= lo && cb + 512 <= hi) {
#pragma unroll
      for (int b = 0; b < 512; b += 256) {
        float4 q0 = kp[b + lane], q1 = kp[b + lane + 64];
        float4 q2 = kp[b + lane + 128], q3 = kp[b + lane + 192];
        float a0 = DIST(q0), a1 = DIST(q1), a2 = DIST(q2), a3 = DIST(q3);
        if (__any((a0 < d2) | (a1 < d2) | (a2 < d2) | (a3 < d2))) {
          INS1(a0, cb + b + lane) INS1(a1, cb + b + lane + 64)
          INS1(a2, cb + b + lane + 128) INS1(a3, cb + b + lane + 192)
        }
      }
    } else {
#pragma unroll
      for (int j = 0; j < 8; j++) {
        int i = lane + 64 * j;
        int e = cb + i;
        if (i < m && e >= lo && e < hi) {
          float4 q = kp[i];
          float dd = DIST(q);
          INS1(dd, e)
        }
      }
    }
  }
#pragma unroll
  for (int off = 1; off < 64; off <<= 1) {
    float e0 = __shfl_xor(d0, off), e1 = __shfl_xor(d1, off), e2 = __shfl_xor(d2, off);
    int j0 = __shfl_xor(i0, off), j1 = __shfl_xor(i1, off), j2 = __shfl_xor(i2, off);
    INS1(e0, j0) INS1(e1, j1) INS1(e2, j2)
  }
#undef DIST
#undef INS1
  // broadcast lane-0 result (kill tie-order divergence across lanes)
  i0 = __shfl(i0, 0); i1 = __shfl(i1, 0); i2 = __shfl(i2, 0);
  d0 = __shfl(d0, 0); d1 = __shfl(d1, 0); d2 = __shfl(d2, 0);
  if (valid && i0 >= 0) {
    float w0 = 1.f / (d0 + 1e-8f), w1 = 1.f / (d1 + 1e-8f), w2 = 1.f / (d2 + 1e-8f);
    float s = w0 + w1 + w2;
    w0 /= s; w1 /= s; w2 /= s;
    int CP = C >> 1;
    for (int cp = lane; cp < CP; cp += 64) {
      h2_t h0 = u2h(fh[(size_t)i0 * CP + cp]);
      h2_t h1 = u2h(fh[(size_t)i1 * CP + cp]);
      h2_t h2v = u2h(fh[(size_t)i2 * CP + cp]);
      int ce = 2 * cp, co = 2 * cp + 1;
      float se = scsh[ce], he = scsh[C + ce];
      float so = scsh[co], ho = scsh[C + co];
      float ae = w0 * fmaxf(fmaf((float)h0[0], se, he), 0.f)
               + w1 * fmaxf(fmaf((float)h1[0], se, he), 0.f)
               + w2 * fmaxf(fmaf((float)h2v[0], se, he), 0.f);
      float ao = w0 * fmaxf(fmaf((float)h0[1], so, ho), 0.f)
               + w1 * fmaxf(fmaf((float)h1[1], so, ho), 0.f)
               + w2 * fmaxf(fmaf((float)h2v[1], so, ho), 0.f);
      *(float2*)(X + (size_t)u * 160 + xoff + ce) = make_float2(ae, ao);
    }
  }
}

// ---------------- extra 1x1 conv, h2 input with fused BN ----------------
__global__ __launch_bounds__(256) void conv1x1_k(const unsigned* __restrict__ fh,
                                                 const float* __restrict__ scsh,
                                                 const float* __restrict__ we, int n,
                                                 float* __restrict__ out) {
  __shared__ float rows[256];
  int t = threadIdx.x;
  int p = blockIdx.x * 4 + (t >> 6), c = t & 63;
  float v = 0.f;
  if (p < n) {
    h2_t h = u2h(fh[(size_t)p * 32 + (c >> 1)]);
    v = fmaxf(fmaf((float)h[c & 1], scsh[c], scsh[64 + c]), 0.f);
  }
  rows[t] = v;
  __syncthreads();
  if (p >= n) return;
  const float* fr = rows + (t >> 6) * 64;
  float a = 0.f;
#pragma unroll 16
  for (int ci = 0; ci < 64; ci++) a = fmaf(fr[ci], we[ci * 64 + c], a);
  out[(size_t)p * 64 + c] = a;
}

// ---------------- dense scatter with fused BN+ReLU ----------------
__global__ void scatter_k(const float* __restrict__ pre, const float* __restrict__ scsh,
                          const int* __restrict__ c3, int n3, float* __restrict__ out0) {
  int t = blockIdx.x * 256 + threadIdx.x;
  if (t >= n3 * 64) return;
  int p = t >> 6, c = t & 63;
  const int* cc = c3 + (size_t)p * 4;
  size_t o = ((((size_t)cc[0] * 64 + c) * 6 + cc[1]) * 100 + cc[2]) * 100 + cc[3];
  out0[o] = fmaxf(fmaf(pre[t], scsh[c], scsh[64 + c]), 0.f);
}

// ---------------- head ----------------
__global__ __launch_bounds__(256) void head_k(const float* __restrict__ X,
                                              const float* __restrict__ fcw,
                                              const float* __restrict__ clsw,
                                              const float* __restrict__ regw,
                                              int n0, float* __restrict__ outc,
                                              float* __restrict__ outr) {
  __shared__ float fl[64 * 161];
  int t = threadIdx.x;
  for (int i = t; i < 64 * 160; i += 256) {
    int r = i / 160, c = i % 160;
    fl[r * 161 + c] = fcw[i];
  }
  __syncthreads();
  int wave = t >> 6, lane = t & 63;
  int u = blockIdx.x * 4 + wave;
  if (u >= n0) return;
  const float* xr = X + (size_t)u * 160;
  const float* wr = fl + (size_t)lane * 161;
  float a = 0.f;
#pragma unroll 8
  for (int i = 0; i < 160; i++) a = fmaf(xr[i], wr[i], a);
  float c = a * clsw[lane];
  float r0 = a * regw[lane], r1 = a * regw[64 + lane], r2 = a * regw[128 + lane];
  for (int off = 32; off; off >>= 1) {
    c  += __shfl_down(c, off);
    r0 += __shfl_down(r0, off);
    r1 += __shfl_down(r1, off);
    r2 += __shfl_down(r2, off);
  }
  if (lane == 0) {
    outc[u] = c;
    outr[(size_t)u * 3] = r0; outr[(size_t)u * 3 + 1] = r1; outr[(size_t)u * 3 + 2] = r2;
  }
}

// ---------------- host ----------------
extern "C" void kernel_launch(void* const* d_in, const int* in_sizes, int n_in,
                              void* d_out, int out_size, void* d_ws, size_t ws_size,
                              hipStream_t stream) {
  const float* vf  = (const float*)d_in[0];
  const int* c0 = (const int*)d_in[1];
  const int* c1 = (const int*)d_in[2];
  const int* c2 = (const int*)d_in[3];
  const int* c3 = (const int*)d_in[4];
  const float* w00 = (const float*)d_in[5];  const float* b00 = (const float*)d_in[6];
  const float* w01 = (const float*)d_in[7];  const float* b01 = (const float*)d_in[8];
  const float* wd0 = (const float*)d_in[9];  const float* bd0 = (const float*)d_in[10];
  const float* w10 = (const float*)d_in[11]; const float* b10 = (const float*)d_in[12];
  const float* w11 = (const float*)d_in[13]; const float* b11 = (const float*)d_in[14];
  const float* wd1 = (const float*)d_in[15]; const float* bd1 = (const float*)d_in[16];
  const float* w20 = (const float*)d_in[17]; const float* b20 = (const float*)d_in[18];
  const float* w21 = (const float*)d_in[19]; const float* b21 = (const float*)d_in[20];
  const float* w22 = (const float*)d_in[21]; const float* b22 = (const float*)d_in[22];
  const float* wd2 = (const float*)d_in[23]; const float* bd2 = (const float*)d_in[24];
  const float* w30 = (const float*)d_in[25]; const float* b30 = (const float*)d_in[26];
  const float* w31 = (const float*)d_in[27]; const float* b31 = (const float*)d_in[28];
  const float* w32 = (const float*)d_in[29]; const float* b32 = (const float*)d_in[30];
  const float* we  = (const float*)d_in[31]; const float* be  = (const float*)d_in[32];
  const float* fcw = (const float*)d_in[33];
  const float* clsw = (const float*)d_in[34];
  const float* regw = (const float*)d_in[35];

  int N0 = in_sizes[1] / 4, N1 = in_sizes[2] / 4, N2 = in_sizes[3] / 4, N3 = in_sizes[4] / 4;
  int maxN = N0; if (N1 > maxN) maxN = N1; if (N2 > maxN) maxN = N2; if (N3 > maxN) maxN = N3;

  auto cdiv = [](int a, int b) { return (a + b - 1) / b; };
  char* p = (char*)d_ws;
  auto alloc = [&](size_t bytes) { char* r = p; p += (bytes + 255) & ~(size_t)255; return r; };

  int* keys0 = (int*)alloc((size_t)N0 * 4);
  int* keys1 = (int*)alloc((size_t)N1 * 4);
  int* keys2 = (int*)alloc((size_t)N2 * 4);
  int* keys3 = (int*)alloc((size_t)N3 * 4);
  int* nbr0  = (int*)alloc((size_t)N0 * 27 * 4);
  int* nbrs1 = (int*)alloc((size_t)N1 * 27 * 4);
  int* nbr1  = (int*)alloc((size_t)N1 * 27 * 4);
  int* nbrs2 = (int*)alloc((size_t)N2 * 27 * 4);
  int* nbr2  = (int*)alloc((size_t)N2 * 27 * 4);
  int* nbrs3 = (int*)alloc((size_t)N3 * 27 * 4);
  int* nbr3  = (int*)alloc((size_t)N3 * 27 * 4);
  float* FB = (float*)alloc((size_t)maxN * 64 * 4);
  float* FC = (float*)alloc((size_t)maxN * 64 * 4);
  unsigned* FAh = (unsigned*)alloc((size_t)maxN * 32 * 4);
  unsigned* FBh = (unsigned*)alloc((size_t)maxN * 32 * 4);
  float* stats = (float*)alloc((size_t)NCH * 64 * 2 * 4);
  float* SC = (float*)alloc((size_t)15 * 128 * 4);
  int* ctrs = (int*)alloc(16 * 4);
  float* X  = (float*)alloc((size_t)N0 * 160 * 4);
  float* pmb = (float*)alloc((size_t)N0 * 4 * 4);
  float4* kp1 = (float4*)alloc((size_t)N1 * 16);
  float4* kp2 = (float4*)alloc((size_t)N2 * 16);
  float4* kp3 = (float4*)alloc((size_t)N3 * 16);
  int* bsA = (int*)alloc(32);
  unsigned* whbuf = (unsigned*)alloc((size_t)452736 * 4);

  float* out0 = (float*)d_out;
  float* out1 = out0 + 7680000;
  float* outc = out1 + (size_t)N0 * 4;
  float* outr = outc + N0;
  void* partial = out0;  // conv partial scratch until final memset

  auto scsh = [&](int L) { return SC + (size_t)L * 128; };

  const float* wsrc[13] = {w01, wd0, w10, w11, wd1, w20, w21, w22, wd2, w30, w31, w32, nullptr};
  int wcin[13]  = {16, 16, 32, 32, 32, 64, 64, 64, 64, 64, 64, 64, 0};
  int wcout[13] = {16, 32, 32, 32, 64, 64, 64, 64, 64, 64, 64, 64, 0};
  unsigned* wdst[13];
  size_t woff = 0;
  WP13 wp{};
  int nw = 12;
  for (int i = 0; i < nw; i++) {
    wdst[i] = whbuf + woff;
    wp.l[i] = WPrep{wsrc[i], wdst[i], wcin[i], wcout[i]};
    woff += (size_t)27 * (wcin[i] / 2) * wcout[i];
  }
  for (int i = nw; i < 13; i++) wp.l[i] = WPrep{w01, wdst[0], 16, 16};

  wprep_k<<<dim3(216, nw), 256, 0, stream>>>(wp);
  PrepA pa;
  pa.c0 = c0; pa.c1 = c1; pa.c2 = c2; pa.c3 = c3;
  pa.n0 = N0; pa.n1 = N1; pa.n2 = N2; pa.n3 = N3;
  pa.k0 = keys0; pa.k1 = keys1; pa.k2 = keys2; pa.k3 = keys3;
  pa.kp1 = kp1; pa.kp2 = kp2; pa.kp3 = kp3;
  pa.bs = bsA; pa.vf = vf; pa.pmb = pmb; pa.out1 = out1;
  pa.ctrs = ctrs;
  prep_k<<<cdiv(maxN, 256), 256, 0, stream>>>(pa);
  NbrA na;
  na.e[0] = NbrE{c0, N0, keys0, N0, 41, 800, 800, 1, nbr0};
  na.e[1] = NbrE{c1, N1, keys0, N0, 41, 800, 800, 2, nbrs1};
  na.e[2] = NbrE{c1, N1, keys1, N1, 21, 400, 400, 1, nbr1};
  na.e[3] = NbrE{c2, N2, keys1, N1, 21, 400, 400, 2, nbrs2};
  na.e[4] = NbrE{c2, N2, keys2, N2, 11, 200, 200, 1, nbr2};
  na.e[5] = NbrE{c3, N3, keys2, N2, 11, 200, 200, 2, nbrs3};
  na.e[6] = NbrE{c3, N3, keys3, N3, 6, 100, 100, 1, nbr3};
  nbra_k<<<dim3(cdiv(maxN * 9, 256), 7), 256, 0, stream>>>(na);

  auto convh = [&](const unsigned* fhin, const int* nb, int wi, int n, int cin, int cout,
                   const float* ss) {
    dim3 g(cdiv(n, 32), NG);
    int gs = (cout >= 32) ? n * cout / 2 : n * cout;  // uints when h2-packed
    const unsigned* wh = wdst[wi];
    if (cin == 16 && cout == 16)
      convh_k<16, 16><<<g, 128, 0, stream>>>(fhin, nb, wh, n, partial, gs, ss);
    else if (cin == 16 && cout == 32)
      convh_k<16, 32><<<g, 128, 0, stream>>>(fhin, nb, wh, n, partial, gs, ss);
    else if (cin == 32 && cout == 32)
      convh_k<32, 32><<<g, 128, 0, stream>>>(fhin, nb, wh, n, partial, gs, ss);
    else if (cin == 32 && cout == 64)
      convh_k<32, 64><<<g, 128, 0, stream>>>(fhin, nb, wh, n, partial, gs, ss);
    else
      convh_k<64, 64><<<g, 128, 0, stream>>>(fhin, nb, wh, n, partial, gs, ss);
  };
  auto bnp = [&](const float* bnpar, int n, int C, float* pre, unsigned* preh, int L, bool h2p) {
    int gs = h2p ? n * C / 2 : n * C;
    if (h2p)
      bn_k<true><<<NCH, 256, 0, stream>>>(partial, NG, gs, n, C, pre, preh, stats, bnpar,
                                          scsh(L), ctrs + L);
    else
      bn_k<false><<<NCH, 256, 0, stream>>>(partial, NG, gs, n, C, pre, preh, stats, bnpar,
                                           scsh(L), ctrs + L);
  };
  auto knn = [&](const float4* kp4, const int* bsl, int nl, const unsigned* fh, int C, int L,
                 int xoff) {
    knni_k<<<cdiv(N0, 4), 256, 0, stream>>>((const float4*)pmb, N0, kp4, nl, bsl,
                                            fh, C, scsh(L), X, xoff);
  };

  // layer 0: fp32 conv from raw voxel features
  convg_k<4, 16><<<dim3(cdiv(N0, 32), NG), 128, 0, stream>>>(vf, nbr0, w00, N0,
                                                             (float*)partial, N0 * 16);
  bnp(b00, N0, 16, nullptr, FAh, 0, false);
  convh(FAh, nbr0, 0, N0, 16, 16, scsh(0));   bnp(b01, N0, 16, nullptr, FBh, 1, false);
  convh(FBh, nbrs1, 1, N1, 16, 32, scsh(1));  bnp(bd0, N1, 32, nullptr, FAh, 2, true);
  convh(FAh, nbr1, 2, N1, 32, 32, scsh(2));   bnp(b10, N1, 32, nullptr, FBh, 3, true);
  convh(FBh, nbr1, 3, N1, 32, 32, scsh(3));   bnp(b11, N1, 32, nullptr, FAh, 4, true);
  knn(kp1, bsA + 0, N1, FAh, 32, 4, 0);
  convh(FAh, nbrs2, 4, N2, 32, 64, scsh(4));  bnp(bd1, N2, 64, nullptr, FBh, 5, true);
  convh(FBh, nbr2, 5, N2, 64, 64, scsh(5));   bnp(b20, N2, 64, nullptr, FAh, 6, true);
  convh(FAh, nbr2, 6, N2, 64, 64, scsh(6));   bnp(b21, N2, 64, nullptr, FBh, 7, true);
  convh(FBh, nbr2, 7, N2, 64, 64, scsh(7));   bnp(b22, N2, 64, nullptr, FAh, 8, true);
  knn(kp2, bsA + 1, N2, FAh, 64, 8, 32);
  convh(FAh, nbrs3, 8, N3, 64, 64, scsh(8));  bnp(bd2, N3, 64, nullptr, FBh, 9, true);
  convh(FBh, nbr3, 9, N3, 64, 64, scsh(9));   bnp(b30, N3, 64, nullptr, FAh, 10, true);
  convh(FAh, nbr3, 10, N3, 64, 64, scsh(10)); bnp(b31, N3, 64, nullptr, FBh, 11, true);
  convh(FBh, nbr3, 11, N3, 64, 64, scsh(11)); bnp(b32, N3, 64, nullptr, FAh, 12, true);
  knn(kp3, bsA + 2, N3, FAh, 64, 12, 96);

  conv1x1_k<<<cdiv(N3, 4), 256, 0, stream>>>(FAh, scsh(12), we, N3, FC);
  bn_k<false><<<NCH, 256, 0, stream>>>(FC, 1, 0, N3, 64, FB, FBh, stats, be, scsh(13),
                                       ctrs + 13);
  hipMemsetAsync(d_out, 0, (size_t)7680000 * 4, stream);
  scatter_k<<<cdiv(N3 * 64, 256), 256, 0, stream>>>(FB, scsh(13), c3, N3, out0);
  head_k<<<cdiv(N0, 4), 256, 0, stream>>>(X, fcw, clsw, regw, N0, outc, outr);
}